// Round 1
// baseline (3034.490 us; speedup 1.0000x reference)
//
#include <hip/hip_runtime.h>
#include <math.h>

#define N_U 60000
#define N_M 20000
#define NN  80000
#define EE  500000
#define BN_EPS 1e-5f

// ---------------- prep: deg=1, zero BN stats, detect edge dtype ----------------
__global__ void prep_kernel(const int* __restrict__ ei32, float* __restrict__ deg,
                            float* __restrict__ sums, float* __restrict__ sumsq,
                            int* __restrict__ flag) {
    int i = blockIdx.x * blockDim.x + threadIdx.x;
    if (i < 256) { sums[i] = 0.f; sumsq[i] = 0.f; }
    for (int j = i; j < NN; j += gridDim.x * blockDim.x) deg[j] = 1.0f;  // self-loop
    if (blockIdx.x == 0) {
        // int64 data read as int32: odd positions are hi-words == 0 (indices < 2^31).
        // int32 data: odd positions are random indices, ~never all zero.
        __shared__ int nz;
        if (threadIdx.x == 0) nz = 0;
        __syncthreads();
        int v = ei32[2 * threadIdx.x + 1];
        if (v != 0) atomicOr(&nz, 1);
        __syncthreads();
        if (threadIdx.x == 0) *flag = (nz == 0) ? 1 : 0;  // 1 -> int64
    }
}

__device__ __forceinline__ int load_idx(const void* ei, int f, int pos) {
    return f ? (int)((const long long*)ei)[pos] : ((const int*)ei)[pos];
}

// ---------------- degree count (dst side, with self-loop pre-init) ----------------
__global__ void deg_count_kernel(const void* __restrict__ ei, const int* __restrict__ flag,
                                 float* __restrict__ deg) {
    int f = *flag;
    int stride = gridDim.x * blockDim.x;
    for (int e = blockIdx.x * blockDim.x + threadIdx.x; e < EE; e += stride) {
        int d = load_idx(ei, f, EE + e);
        atomicAdd(&deg[d], 1.0f);
    }
}

__global__ void rsqrt_kernel(float* __restrict__ deg) {
    int i = blockIdx.x * blockDim.x + threadIdx.x;
    if (i < NN) deg[i] = rsqrtf(deg[i]);
}

// ---------------- f32 GEMM: Out[M,N] = A[M,K] @ W[K,N] (+bias) ----------------
// block=256 threads, BM=32 rows/block, per-thread 8x4 (N=256) or 4x4 (N=128) outputs
template <int K, int N, bool HAS_BIAS>
__global__ __launch_bounds__(256) void gemm_kernel(const float* __restrict__ A,
                                                   const float* __restrict__ W,
                                                   const float* __restrict__ bias,
                                                   float* __restrict__ Out) {
    constexpr int BM = 32, KT = 32;
    constexpr int NQ = N / 4;        // col quads: 64 or 32
    constexpr int NG = 256 / NQ;     // row groups: 4 or 8
    constexpr int R  = BM / NG;      // rows/thread: 8 or 4
    __shared__ float As[BM][KT];
    __shared__ float Ws[KT][N];
    const int tid = threadIdx.x;
    const int q = tid % NQ, g = tid / NQ;
    const int brow = blockIdx.x * BM;

    float acc[R][4];
#pragma unroll
    for (int r = 0; r < R; ++r) {
        if (HAS_BIAS) {
            acc[r][0] = bias[4 * q + 0]; acc[r][1] = bias[4 * q + 1];
            acc[r][2] = bias[4 * q + 2]; acc[r][3] = bias[4 * q + 3];
        } else {
            acc[r][0] = acc[r][1] = acc[r][2] = acc[r][3] = 0.f;
        }
    }

    for (int k0 = 0; k0 < K; k0 += KT) {
        {   // A tile: 32x32 = 256 float4
            int row = tid >> 3, kq = tid & 7;
            *(float4*)&As[row][4 * kq] =
                *(const float4*)&A[(size_t)(brow + row) * K + k0 + 4 * kq];
        }
#pragma unroll
        for (int i = 0; i < KT * NQ / 256; ++i) {  // W tile: KTxN
            int p = tid + 256 * i;
            int kr = p / NQ, c4 = p % NQ;
            *(float4*)&Ws[kr][4 * c4] =
                *(const float4*)&W[(size_t)(k0 + kr) * N + 4 * c4];
        }
        __syncthreads();
#pragma unroll
        for (int kk4 = 0; kk4 < KT / 4; ++kk4) {
            float4 av[R];
#pragma unroll
            for (int r = 0; r < R; ++r)
                av[r] = *(float4*)&As[g + NG * r][4 * kk4];
#pragma unroll
            for (int j = 0; j < 4; ++j) {
                float4 wv = *(float4*)&Ws[4 * kk4 + j][4 * q];
#pragma unroll
                for (int r = 0; r < R; ++r) {
                    float a = (j == 0) ? av[r].x : (j == 1) ? av[r].y
                              : (j == 2) ? av[r].z : av[r].w;
                    acc[r][0] += a * wv.x; acc[r][1] += a * wv.y;
                    acc[r][2] += a * wv.z; acc[r][3] += a * wv.w;
                }
            }
        }
        __syncthreads();
    }
#pragma unroll
    for (int r = 0; r < R; ++r)
        *(float4*)&Out[(size_t)(brow + g + NG * r) * N + 4 * q] = *(float4*)&acc[r][0];
}

// ---------------- aggregation init: out = bias + h*dinv^2 (self loop) ----------------
template <int C>
__global__ void agg_init_kernel(const float* __restrict__ h, const float* __restrict__ bias,
                                const float* __restrict__ dinv, float* __restrict__ out) {
    constexpr int CQ = C / 4;
    int stride = gridDim.x * blockDim.x;
    for (int idx = blockIdx.x * blockDim.x + threadIdx.x; idx < NN * CQ; idx += stride) {
        int row = idx / CQ, qq = idx - row * CQ;
        float di = dinv[row];
        float c = di * di;
        float4 v = *(const float4*)&h[(size_t)row * C + 4 * qq];
        float4 b = *(const float4*)&bias[4 * qq];
        float4 o;
        o.x = b.x + v.x * c; o.y = b.y + v.y * c;
        o.z = b.z + v.z * c; o.w = b.w + v.w * c;
        *(float4*)&out[(size_t)row * C + 4 * qq] = o;
    }
}

// ---------------- edge scatter: out[dst] += h[src] * dinv[src]*dinv[dst] ----------------
template <int C>
__global__ void agg_edge_kernel(const void* __restrict__ ei, const int* __restrict__ flag,
                                const float* __restrict__ dinv, const float* __restrict__ h,
                                float* __restrict__ out) {
    constexpr int CQ = C / 4;
    const int f = *flag;
    int stride = gridDim.x * blockDim.x;
    for (int idx = blockIdx.x * blockDim.x + threadIdx.x; idx < EE * CQ; idx += stride) {
        int e = idx / CQ, qq = idx - e * CQ;
        int s = load_idx(ei, f, e);
        int d = load_idx(ei, f, EE + e);
        float coef = dinv[s] * dinv[d];
        float4 v = *(const float4*)&h[(size_t)s * C + 4 * qq];
        float* o = out + (size_t)d * C + 4 * qq;
        atomicAdd(o + 0, v.x * coef);
        atomicAdd(o + 1, v.y * coef);
        atomicAdd(o + 2, v.z * coef);
        atomicAdd(o + 3, v.w * coef);
    }
}

// ---------------- BN stats / finalize / apply+relu ----------------
__global__ void bn_stats_kernel(const float* __restrict__ a, float* __restrict__ sums,
                                float* __restrict__ sumsq) {
    int c = threadIdx.x;  // 256 channels
    float s = 0.f, s2 = 0.f;
    for (int row = blockIdx.x; row < NN; row += gridDim.x) {
        float v = a[(size_t)row * 256 + c];
        s += v; s2 += v * v;
    }
    atomicAdd(&sums[c], s);
    atomicAdd(&sumsq[c], s2);
}

__global__ void bn_final_kernel(const float* __restrict__ sums, const float* __restrict__ sumsq,
                                const float* __restrict__ gamma, const float* __restrict__ beta,
                                float* __restrict__ scale, float* __restrict__ shift) {
    int c = threadIdx.x;
    const float Nf = (float)NN;
    float mean = sums[c] / Nf;
    float var = sumsq[c] / Nf - mean * mean;
    float sc = gamma[c] * rsqrtf(var + BN_EPS);
    scale[c] = sc;
    shift[c] = beta[c] - mean * sc;
}

__global__ void bn_apply_relu_kernel(float* __restrict__ a, const float* __restrict__ scale,
                                     const float* __restrict__ shift) {
    int stride = gridDim.x * blockDim.x;
    for (int idx = blockIdx.x * blockDim.x + threadIdx.x; idx < NN * 64; idx += stride) {
        int qq = idx & 63;
        float4 v = *(float4*)&a[(size_t)idx * 4];
        float4 sc = *(const float4*)&scale[4 * qq];
        float4 sh = *(const float4*)&shift[4 * qq];
        v.x = fmaxf(v.x * sc.x + sh.x, 0.f);
        v.y = fmaxf(v.y * sc.y + sh.y, 0.f);
        v.z = fmaxf(v.z * sc.z + sh.z, 0.f);
        v.w = fmaxf(v.w * sc.w + sh.w, 0.f);
        *(float4*)&a[(size_t)idx * 4] = v;
    }
}

extern "C" void kernel_launch(void* const* d_in, const int* in_sizes, int n_in,
                              void* d_out, int out_size, void* d_ws, size_t ws_size,
                              hipStream_t stream) {
    const float* x       = (const float*)d_in[0];
    const float* y       = (const float*)d_in[1];
    const void*  ei      = d_in[2];
    const float* fc1_w   = (const float*)d_in[3];
    const float* fc1_b   = (const float*)d_in[4];
    const float* fc2_w   = (const float*)d_in[5];
    const float* fc2_b   = (const float*)d_in[6];
    const float* conv1_w = (const float*)d_in[7];
    const float* conv1_b = (const float*)d_in[8];
    const float* conv2_w = (const float*)d_in[9];
    const float* conv2_b = (const float*)d_in[10];
    const float* gamma   = (const float*)d_in[11];
    const float* beta    = (const float*)d_in[12];
    float* out = (float*)d_out;

    float* ws = (float*)d_ws;
    float* bufA = ws;                       // 80000*256 floats: z0, then a1
    float* bufB = ws + (size_t)NN * 256;    // 80000*256 floats: h1, then h2
    float* aux  = bufB + (size_t)NN * 256;
    float* deg   = aux;            // 80000 (becomes dinv)
    float* sums  = aux + NN;       // 256
    float* sumsq = sums + 256;     // 256
    float* scale = sumsq + 256;    // 256
    float* shift = scale + 256;    // 256
    int*   flag  = (int*)(shift + 256);

    prep_kernel<<<320, 256, 0, stream>>>((const int*)ei, deg, sums, sumsq, flag);
    deg_count_kernel<<<1024, 256, 0, stream>>>(ei, flag, deg);
    rsqrt_kernel<<<(NN + 255) / 256, 256, 0, stream>>>(deg);

    // input projections -> z0 in bufA
    gemm_kernel<64, 256, true><<<N_U / 32, 256, 0, stream>>>(x, fc1_w, fc1_b, bufA);
    gemm_kernel<128, 256, true><<<N_M / 32, 256, 0, stream>>>(y, fc2_w, fc2_b,
                                                              bufA + (size_t)N_U * 256);
    // conv1 transform: h1 = z0 @ W1 -> bufB
    gemm_kernel<256, 256, false><<<NN / 32, 256, 0, stream>>>(bufA, conv1_w, nullptr, bufB);
    // conv1 aggregate -> a1 in bufA
    agg_init_kernel<256><<<2048, 256, 0, stream>>>(bufB, conv1_b, deg, bufA);
    agg_edge_kernel<256><<<2048, 256, 0, stream>>>(ei, flag, deg, bufB, bufA);
    // BN + ReLU in place on bufA
    bn_stats_kernel<<<256, 256, 0, stream>>>(bufA, sums, sumsq);
    bn_final_kernel<<<1, 256, 0, stream>>>(sums, sumsq, gamma, beta, scale, shift);
    bn_apply_relu_kernel<<<2048, 256, 0, stream>>>(bufA, scale, shift);
    // conv2 transform: h2 = a1 @ W2 -> bufB
    gemm_kernel<256, 128, false><<<NN / 32, 256, 0, stream>>>(bufA, conv2_w, nullptr, bufB);
    // conv2 aggregate -> d_out
    agg_init_kernel<128><<<2048, 256, 0, stream>>>(bufB, conv2_b, deg, out);
    agg_edge_kernel<128><<<2048, 256, 0, stream>>>(ei, flag, deg, bufB, out);
}

// Round 4
// 753.352 us; speedup vs baseline: 4.0280x; 4.0280x over previous
//
#include <hip/hip_runtime.h>
#include <math.h>

#define N_U 60000
#define N_M 20000
#define NN  80000
#define EE  500000
#define BN_EPS 1e-5f
#define NB_SCAN 313   // ceil(80000/256)

// ---------------- prep: zero cnt/cursor/BN stats, rowptr[NN]=EE, detect edge dtype ----
__global__ void prep_kernel(const int* __restrict__ ei32, int* __restrict__ cnt,
                            int* __restrict__ cursor, int* __restrict__ rowptr,
                            float* __restrict__ sums, float* __restrict__ sumsq,
                            int* __restrict__ flag) {
    int i = blockIdx.x * blockDim.x + threadIdx.x;
    if (i < 256) { sums[i] = 0.f; sumsq[i] = 0.f; }
    for (int j = i; j < NN; j += gridDim.x * blockDim.x) { cnt[j] = 0; cursor[j] = 0; }
    if (i == 0) rowptr[NN] = EE;
    if (blockIdx.x == 0) {
        // int64 read as int32: odd words are hi-words == 0. int32 data: ~never all zero.
        __shared__ int nz;
        if (threadIdx.x == 0) nz = 0;
        __syncthreads();
        int v = ei32[2 * threadIdx.x + 1];
        if (v != 0) atomicOr(&nz, 1);
        __syncthreads();
        if (threadIdx.x == 0) *flag = (nz == 0) ? 1 : 0;  // 1 -> int64
    }
}

__device__ __forceinline__ int load_idx(const void* ei, int f, int pos) {
    return f ? (int)((const long long*)ei)[pos] : ((const int*)ei)[pos];
}

// ---------------- degree histogram (dst side, edges only) ----------------
__global__ void hist_kernel(const void* __restrict__ ei, const int* __restrict__ flag,
                            int* __restrict__ cnt) {
    int f = *flag;
    int stride = gridDim.x * blockDim.x;
    for (int e = blockIdx.x * blockDim.x + threadIdx.x; e < EE; e += stride) {
        int d = load_idx(ei, f, EE + e);
        atomicAdd(&cnt[d], 1);
    }
}

__global__ void dinv_kernel(const int* __restrict__ cnt, float* __restrict__ dinv) {
    int i = blockIdx.x * blockDim.x + threadIdx.x;
    if (i < NN) dinv[i] = rsqrtf(1.0f + (float)cnt[i]);   // +1 self-loop
}

// ---------------- exclusive scan of cnt -> rowptr (3 kernels) ----------------
__global__ void scan1_kernel(const int* __restrict__ cnt, int* __restrict__ rowptr,
                             int* __restrict__ blockSums) {
    __shared__ int sh[256];
    int tid = threadIdx.x;
    int i = blockIdx.x * 256 + tid;
    int v = (i < NN) ? cnt[i] : 0;
    int x = v;
    sh[tid] = x; __syncthreads();
#pragma unroll
    for (int off = 1; off < 256; off <<= 1) {
        int t = (tid >= off) ? sh[tid - off] : 0;
        __syncthreads();
        x += t; sh[tid] = x;
        __syncthreads();
    }
    if (i < NN) rowptr[i] = x - v;                 // exclusive within block
    if (tid == 255) blockSums[blockIdx.x] = x;     // block total
}

__global__ void scan2_kernel(int* __restrict__ blockSums) {
    __shared__ int sh[512];
    int tid = threadIdx.x;
    int v = (tid < NB_SCAN) ? blockSums[tid] : 0;
    int x = v;
    sh[tid] = x; __syncthreads();
#pragma unroll
    for (int off = 1; off < 512; off <<= 1) {
        int t = (tid >= off) ? sh[tid - off] : 0;
        __syncthreads();
        x += t; sh[tid] = x;
        __syncthreads();
    }
    if (tid < NB_SCAN) blockSums[tid] = x - v;     // exclusive block offsets
}

__global__ void scan3_kernel(int* __restrict__ rowptr, const int* __restrict__ blockSums) {
    int i = blockIdx.x * 256 + threadIdx.x;
    if (i < NN) rowptr[i] += blockSums[blockIdx.x];
}

// ---------------- CSR fill: csr_src grouped by dst ----------------
__global__ void fill_kernel(const void* __restrict__ ei, const int* __restrict__ flag,
                            const int* __restrict__ rowptr, int* __restrict__ cursor,
                            int* __restrict__ csr_src) {
    int f = *flag;
    int stride = gridDim.x * blockDim.x;
    for (int e = blockIdx.x * blockDim.x + threadIdx.x; e < EE; e += stride) {
        int s = load_idx(ei, f, e);
        int d = load_idx(ei, f, EE + e);
        int pos = rowptr[d] + atomicAdd(&cursor[d], 1);
        csr_src[pos] = s;
    }
}

// ---------------- f32 GEMM: Out[M,N] = A[M,K] @ W[K,N] (+bias, opt row-scale) --------
// block=256, BM=32 rows/block, per-thread 8x4 (N=256) or 4x4 (N=128) outputs
template <int K, int N, bool HAS_BIAS, bool SCALE>
__global__ __launch_bounds__(256) void gemm_kernel(const float* __restrict__ A,
                                                   const float* __restrict__ W,
                                                   const float* __restrict__ bias,
                                                   const float* __restrict__ rowscale,
                                                   float* __restrict__ Out) {
    constexpr int BM = 32, KT = 32;
    constexpr int NQ = N / 4;        // col quads: 64 or 32
    constexpr int NG = 256 / NQ;     // row groups: 4 or 8
    constexpr int R  = BM / NG;      // rows/thread: 8 or 4
    __shared__ float As[BM][KT];
    __shared__ float Ws[KT][N];
    const int tid = threadIdx.x;
    const int q = tid % NQ, g = tid / NQ;
    const int brow = blockIdx.x * BM;

    float acc[R][4];
#pragma unroll
    for (int r = 0; r < R; ++r) {
        if (HAS_BIAS) {
            acc[r][0] = bias[4 * q + 0]; acc[r][1] = bias[4 * q + 1];
            acc[r][2] = bias[4 * q + 2]; acc[r][3] = bias[4 * q + 3];
        } else {
            acc[r][0] = acc[r][1] = acc[r][2] = acc[r][3] = 0.f;
        }
    }

    for (int k0 = 0; k0 < K; k0 += KT) {
        {   // A tile: 32x32 = 256 float4
            int row = tid >> 3, kq = tid & 7;
            *(float4*)&As[row][4 * kq] =
                *(const float4*)&A[(size_t)(brow + row) * K + k0 + 4 * kq];
        }
#pragma unroll
        for (int i = 0; i < KT * NQ / 256; ++i) {  // W tile: KTxN
            int p = tid + 256 * i;
            int kr = p / NQ, c4 = p % NQ;
            *(float4*)&Ws[kr][4 * c4] =
                *(const float4*)&W[(size_t)(k0 + kr) * N + 4 * c4];
        }
        __syncthreads();
#pragma unroll
        for (int kk4 = 0; kk4 < KT / 4; ++kk4) {
            float4 av[R];
#pragma unroll
            for (int r = 0; r < R; ++r)
                av[r] = *(float4*)&As[g + NG * r][4 * kk4];
#pragma unroll
            for (int j = 0; j < 4; ++j) {
                float4 wv = *(float4*)&Ws[4 * kk4 + j][4 * q];
#pragma unroll
                for (int r = 0; r < R; ++r) {
                    float a = (j == 0) ? av[r].x : (j == 1) ? av[r].y
                              : (j == 2) ? av[r].z : av[r].w;
                    acc[r][0] += a * wv.x; acc[r][1] += a * wv.y;
                    acc[r][2] += a * wv.z; acc[r][3] += a * wv.w;
                }
            }
        }
        __syncthreads();
    }
#pragma unroll
    for (int r = 0; r < R; ++r) {
        int row = brow + g + NG * r;
        float sc = SCALE ? rowscale[row] : 1.0f;
        float4 o;
        o.x = acc[r][0] * sc; o.y = acc[r][1] * sc;
        o.z = acc[r][2] * sc; o.w = acc[r][3] * sc;
        *(float4*)&Out[(size_t)row * N + 4 * q] = o;
    }
}

// ---------------- gather aggregation (no atomics) ----------------
// h is pre-scaled by dinv[row]:  out[d] = bias + dinv[d]*( h'[d] + sum_{s in N(d)} h'[s] )
__global__ __launch_bounds__(256) void gather256_kernel(const float* __restrict__ h,
                                                        const float* __restrict__ bias,
                                                        const float* __restrict__ dinv,
                                                        const int* __restrict__ rowptr,
                                                        const int* __restrict__ csr_src,
                                                        float* __restrict__ out) {
    int wid = threadIdx.x >> 6, lane = threadIdx.x & 63;
    int r = blockIdx.x * 4 + wid;
    if (r >= NN) return;
    int beg = rowptr[r], end = rowptr[r + 1];
    float dr = dinv[r];
    float4 acc = ((const float4*)(h + (size_t)r * 256))[lane];   // self (pre-scaled)
    for (int k = beg; k < end; ++k) {
        int s = csr_src[k];
        float4 v = ((const float4*)(h + (size_t)s * 256))[lane];
        acc.x += v.x; acc.y += v.y; acc.z += v.z; acc.w += v.w;
    }
    float4 b = ((const float4*)bias)[lane];
    float4 o;
    o.x = b.x + dr * acc.x; o.y = b.y + dr * acc.y;
    o.z = b.z + dr * acc.z; o.w = b.w + dr * acc.w;
    ((float4*)(out + (size_t)r * 256))[lane] = o;
}

__global__ __launch_bounds__(256) void gather128_kernel(const float* __restrict__ h,
                                                        const float* __restrict__ bias,
                                                        const float* __restrict__ dinv,
                                                        const int* __restrict__ rowptr,
                                                        const int* __restrict__ csr_src,
                                                        float* __restrict__ out) {
    int sub = threadIdx.x >> 5, lane = threadIdx.x & 31;   // half-wave per row
    int r = blockIdx.x * 8 + sub;
    if (r >= NN) return;
    int beg = rowptr[r], end = rowptr[r + 1];
    float dr = dinv[r];
    float4 acc = ((const float4*)(h + (size_t)r * 128))[lane];
    for (int k = beg; k < end; ++k) {
        int s = csr_src[k];
        float4 v = ((const float4*)(h + (size_t)s * 128))[lane];
        acc.x += v.x; acc.y += v.y; acc.z += v.z; acc.w += v.w;
    }
    float4 b = ((const float4*)bias)[lane];
    float4 o;
    o.x = b.x + dr * acc.x; o.y = b.y + dr * acc.y;
    o.z = b.z + dr * acc.z; o.w = b.w + dr * acc.w;
    ((float4*)(out + (size_t)r * 128))[lane] = o;
}

// ---------------- BN stats / finalize / apply+relu ----------------
__global__ void bn_stats_kernel(const float* __restrict__ a, float* __restrict__ sums,
                                float* __restrict__ sumsq) {
    int c = threadIdx.x;  // 256 channels
    float s = 0.f, s2 = 0.f;
    for (int row = blockIdx.x; row < NN; row += gridDim.x) {
        float v = a[(size_t)row * 256 + c];
        s += v; s2 += v * v;
    }
    atomicAdd(&sums[c], s);
    atomicAdd(&sumsq[c], s2);
}

__global__ void bn_final_kernel(const float* __restrict__ sums, const float* __restrict__ sumsq,
                                const float* __restrict__ gamma, const float* __restrict__ beta,
                                float* __restrict__ scale, float* __restrict__ shift) {
    int c = threadIdx.x;
    const float Nf = (float)NN;
    float mean = sums[c] / Nf;
    float var = sumsq[c] / Nf - mean * mean;
    float sc = gamma[c] * rsqrtf(var + BN_EPS);
    scale[c] = sc;
    shift[c] = beta[c] - mean * sc;
}

__global__ void bn_apply_relu_kernel(float* __restrict__ a, const float* __restrict__ scale,
                                     const float* __restrict__ shift) {
    int stride = gridDim.x * blockDim.x;
    for (int idx = blockIdx.x * blockDim.x + threadIdx.x; idx < NN * 64; idx += stride) {
        int qq = idx & 63;
        float4 v = *(float4*)&a[(size_t)idx * 4];
        float4 sc = *(const float4*)&scale[4 * qq];
        float4 sh = *(const float4*)&shift[4 * qq];
        v.x = fmaxf(v.x * sc.x + sh.x, 0.f);
        v.y = fmaxf(v.y * sc.y + sh.y, 0.f);
        v.z = fmaxf(v.z * sc.z + sh.z, 0.f);
        v.w = fmaxf(v.w * sc.w + sh.w, 0.f);
        *(float4*)&a[(size_t)idx * 4] = v;
    }
}

extern "C" void kernel_launch(void* const* d_in, const int* in_sizes, int n_in,
                              void* d_out, int out_size, void* d_ws, size_t ws_size,
                              hipStream_t stream) {
    const float* x       = (const float*)d_in[0];
    const float* y       = (const float*)d_in[1];
    const void*  ei      = d_in[2];
    const float* fc1_w   = (const float*)d_in[3];
    const float* fc1_b   = (const float*)d_in[4];
    const float* fc2_w   = (const float*)d_in[5];
    const float* fc2_b   = (const float*)d_in[6];
    const float* conv1_w = (const float*)d_in[7];
    const float* conv1_b = (const float*)d_in[8];
    const float* conv2_w = (const float*)d_in[9];
    const float* conv2_b = (const float*)d_in[10];
    const float* gamma   = (const float*)d_in[11];
    const float* beta    = (const float*)d_in[12];
    float* out = (float*)d_out;

    float* ws = (float*)d_ws;
    float* bufA = ws;                       // NN*256: z0, then a1
    float* bufB = ws + (size_t)NN * 256;    // NN*256: h1', then h2'
    float* aux  = bufB + (size_t)NN * 256;
    float* dinv  = aux;                      // NN
    float* sums  = dinv + NN;                // 256
    float* sumsq = sums + 256;               // 256
    float* scale = sumsq + 256;              // 256
    float* shift = scale + 256;              // 256
    int*   flag      = (int*)(shift + 256);  // 1
    int*   cnt       = flag + 1;             // NN
    int*   rowptr    = cnt + NN;             // NN+1
    int*   cursor    = rowptr + NN + 1;      // NN
    int*   blockSums = cursor + NN;          // NB_SCAN
    int*   csr_src   = blockSums + NB_SCAN + 3;  // EE

    // ---- CSR build ----
    prep_kernel<<<320, 256, 0, stream>>>((const int*)ei, cnt, cursor, rowptr, sums, sumsq, flag);
    hist_kernel<<<1024, 256, 0, stream>>>(ei, flag, cnt);
    dinv_kernel<<<(NN + 255) / 256, 256, 0, stream>>>(cnt, dinv);
    scan1_kernel<<<NB_SCAN, 256, 0, stream>>>(cnt, rowptr, blockSums);
    scan2_kernel<<<1, 512, 0, stream>>>(blockSums);
    scan3_kernel<<<NB_SCAN, 256, 0, stream>>>(rowptr, blockSums);
    fill_kernel<<<1024, 256, 0, stream>>>(ei, flag, rowptr, cursor, csr_src);

    // ---- input projections -> z0 in bufA ----
    gemm_kernel<64, 256, true, false><<<N_U / 32, 256, 0, stream>>>(x, fc1_w, fc1_b, nullptr, bufA);
    gemm_kernel<128, 256, true, false><<<N_M / 32, 256, 0, stream>>>(y, fc2_w, fc2_b, nullptr,
                                                                     bufA + (size_t)N_U * 256);
    // ---- conv1: h1' = (z0 @ W1) * dinv[row] -> bufB; gather -> a1 in bufA ----
    gemm_kernel<256, 256, false, true><<<NN / 32, 256, 0, stream>>>(bufA, conv1_w, nullptr, dinv, bufB);
    gather256_kernel<<<NN / 4, 256, 0, stream>>>(bufB, conv1_b, dinv, rowptr, csr_src, bufA);

    // ---- BN + ReLU in place on bufA ----
    bn_stats_kernel<<<256, 256, 0, stream>>>(bufA, sums, sumsq);
    bn_final_kernel<<<1, 256, 0, stream>>>(sums, sumsq, gamma, beta, scale, shift);
    bn_apply_relu_kernel<<<2048, 256, 0, stream>>>(bufA, scale, shift);

    // ---- conv2: h2' = (a1 @ W2) * dinv[row] -> bufB; gather -> d_out ----
    gemm_kernel<256, 128, false, true><<<NN / 32, 256, 0, stream>>>(bufA, conv2_w, nullptr, dinv, bufB);
    gather128_kernel<<<NN / 8, 256, 0, stream>>>(bufB, conv2_b, dinv, rowptr, csr_src, out);
}

// Round 5
// 547.573 us; speedup vs baseline: 5.5417x; 1.3758x over previous
//
#include <hip/hip_runtime.h>
#include <math.h>
#include <stdint.h>

#define N_U 60000
#define N_M 20000
#define NN  80000
#define EE  500000
#define BN_EPS 1e-5f
#define NB_SCAN 313   // ceil(80000/256)

typedef __attribute__((ext_vector_type(8))) short short8v;   // 8 bf16 = 4 VGPR (MFMA A/B frag)
typedef __attribute__((ext_vector_type(4))) float f32x4;     // MFMA C/D frag

// ---------------- bf16 split helpers ----------------
__device__ __forceinline__ unsigned short bf_hi(float f) {
    unsigned u = __float_as_uint(f);
    return (unsigned short)((u + 0x7FFFu + ((u >> 16) & 1u)) >> 16);   // RNE
}
__device__ __forceinline__ float bf_f(unsigned short h) {
    return __uint_as_float(((unsigned)h) << 16);
}

// ---------------- prep: zero cnt/cursor/BN stats, rowptr[NN]=EE, detect edge dtype ----
__global__ void prep_kernel(const int* __restrict__ ei32, int* __restrict__ cnt,
                            int* __restrict__ cursor, int* __restrict__ rowptr,
                            float* __restrict__ sums, float* __restrict__ sumsq,
                            int* __restrict__ flag) {
    int i = blockIdx.x * blockDim.x + threadIdx.x;
    if (i < 256) { sums[i] = 0.f; sumsq[i] = 0.f; }
    for (int j = i; j < NN; j += gridDim.x * blockDim.x) { cnt[j] = 0; cursor[j] = 0; }
    if (i == 0) rowptr[NN] = EE;
    if (blockIdx.x == 0) {
        __shared__ int nz;
        if (threadIdx.x == 0) nz = 0;
        __syncthreads();
        int v = ei32[2 * threadIdx.x + 1];
        if (v != 0) atomicOr(&nz, 1);
        __syncthreads();
        if (threadIdx.x == 0) *flag = (nz == 0) ? 1 : 0;  // 1 -> int64
    }
}

__device__ __forceinline__ int load_idx(const void* ei, int f, int pos) {
    return f ? (int)((const long long*)ei)[pos] : ((const int*)ei)[pos];
}

// ---------------- degree histogram (dst side, edges only) ----------------
__global__ void hist_kernel(const void* __restrict__ ei, const int* __restrict__ flag,
                            int* __restrict__ cnt) {
    int f = *flag;
    int stride = gridDim.x * blockDim.x;
    for (int e = blockIdx.x * blockDim.x + threadIdx.x; e < EE; e += stride) {
        int d = load_idx(ei, f, EE + e);
        atomicAdd(&cnt[d], 1);
    }
}

__global__ void dinv_kernel(const int* __restrict__ cnt, float* __restrict__ dinv) {
    int i = blockIdx.x * blockDim.x + threadIdx.x;
    if (i < NN) dinv[i] = rsqrtf(1.0f + (float)cnt[i]);   // +1 self-loop
}

// ---------------- exclusive scan of cnt -> rowptr (3 kernels) ----------------
__global__ void scan1_kernel(const int* __restrict__ cnt, int* __restrict__ rowptr,
                             int* __restrict__ blockSums) {
    __shared__ int sh[256];
    int tid = threadIdx.x;
    int i = blockIdx.x * 256 + tid;
    int v = (i < NN) ? cnt[i] : 0;
    int x = v;
    sh[tid] = x; __syncthreads();
#pragma unroll
    for (int off = 1; off < 256; off <<= 1) {
        int t = (tid >= off) ? sh[tid - off] : 0;
        __syncthreads();
        x += t; sh[tid] = x;
        __syncthreads();
    }
    if (i < NN) rowptr[i] = x - v;
    if (tid == 255) blockSums[blockIdx.x] = x;
}

__global__ void scan2_kernel(int* __restrict__ blockSums) {
    __shared__ int sh[512];
    int tid = threadIdx.x;
    int v = (tid < NB_SCAN) ? blockSums[tid] : 0;
    int x = v;
    sh[tid] = x; __syncthreads();
#pragma unroll
    for (int off = 1; off < 512; off <<= 1) {
        int t = (tid >= off) ? sh[tid - off] : 0;
        __syncthreads();
        x += t; sh[tid] = x;
        __syncthreads();
    }
    if (tid < NB_SCAN) blockSums[tid] = x - v;
}

__global__ void scan3_kernel(int* __restrict__ rowptr, const int* __restrict__ blockSums) {
    int i = blockIdx.x * 256 + threadIdx.x;
    if (i < NN) rowptr[i] += blockSums[blockIdx.x];
}

// ---------------- CSR fill: csr_src grouped by dst ----------------
__global__ void fill_kernel(const void* __restrict__ ei, const int* __restrict__ flag,
                            const int* __restrict__ rowptr, int* __restrict__ cursor,
                            int* __restrict__ csr_src) {
    int f = *flag;
    int stride = gridDim.x * blockDim.x;
    for (int e = blockIdx.x * blockDim.x + threadIdx.x; e < EE; e += stride) {
        int s = load_idx(ei, f, e);
        int d = load_idx(ei, f, EE + e);
        int pos = rowptr[d] + atomicAdd(&cursor[d], 1);
        csr_src[pos] = s;
    }
}

// ---------------- W transpose + bf16 split (once per launch, tiny) ----------------
// W[K][N] f32 row-major -> Wt_hi/Wt_lo [N][K] bf16
__global__ void wsplit_kernel(const float* __restrict__ W1, const float* __restrict__ W2,
                              short* __restrict__ W1tHi, short* __restrict__ W1tLo,
                              short* __restrict__ W2tHi, short* __restrict__ W2tLo) {
    int i = blockIdx.x * 256 + threadIdx.x;   // grid covers 65536
    if (i < 256 * 256) {
        int k = i >> 8, n = i & 255;
        float v = W1[i];
        unsigned short h = bf_hi(v);
        unsigned short l = bf_hi(v - bf_f(h));
        W1tHi[n * 256 + k] = (short)h;
        W1tLo[n * 256 + k] = (short)l;
    }
    if (i < 256 * 128) {
        int k = i >> 7, n = i & 127;
        float v = W2[i];
        unsigned short h = bf_hi(v);
        unsigned short l = bf_hi(v - bf_f(h));
        W2tHi[n * 256 + k] = (short)h;
        W2tLo[n * 256 + k] = (short)l;
    }
}

// ---------------- split-bf16 MFMA GEMM: Out[M,N] = (A f32 @ W) * dinv[row] ----------
// Block: 256 thr (4 waves, 2x2 of 64x64), tile 128x128, BK=32.
// A[M][K] f32 (split to bf16 hi/lo in-kernel), W pre-split transposed [N][K] bf16.
// Error: ~2^-17 relative (AhWh + AhWl + AlWh, fp32 accum).
template <int K, int N>
__global__ __launch_bounds__(256) void mfma_gemm_kernel(
    const float* __restrict__ A, const short* __restrict__ WtHi,
    const short* __restrict__ WtLo, const float* __restrict__ rowscale,
    float* __restrict__ Out) {
    constexpr int LDT = 40;   // padded LDS row stride (bf16): 80 B = 20 banks -> 2-way max
    __shared__ short AsHi[128 * LDT];
    __shared__ short AsLo[128 * LDT];
    __shared__ short BsHi[128 * LDT];
    __shared__ short BsLo[128 * LDT];
    const int tid  = threadIdx.x;
    const int lane = tid & 63, wave = tid >> 6;
    const int wm = (wave >> 1) * 64, wn = (wave & 1) * 64;
    const int R0 = blockIdx.x * 128;
    const int n0 = blockIdx.y * 128;
    const int srow  = tid >> 1;          // staging row 0..127 (2 thr/row)
    const int shalf = (tid & 1) * 16;    // element offset 0 / 16
    const int l15  = lane & 15;
    const int koff = (lane >> 4) * 8;    // k-slice base per lane

    f32x4 acc[4][4];
#pragma unroll
    for (int mi = 0; mi < 4; ++mi)
#pragma unroll
        for (int ni = 0; ni < 4; ++ni)
            acc[mi][ni] = (f32x4){0.f, 0.f, 0.f, 0.f};

    for (int k0 = 0; k0 < K; k0 += 32) {
        // ---- global loads (issued before barrier; latency overlaps prior compute) ----
        const float4* ga = (const float4*)&A[(size_t)(R0 + srow) * K + k0 + shalf];
        float4 a0 = ga[0], a1 = ga[1], a2 = ga[2], a3 = ga[3];
        const int4* gwh = (const int4*)&WtHi[(size_t)(n0 + srow) * K + k0 + shalf];
        const int4* gwl = (const int4*)&WtLo[(size_t)(n0 + srow) * K + k0 + shalf];
        int4 wh0 = gwh[0], wh1 = gwh[1];
        int4 wl0 = gwl[0], wl1 = gwl[1];

        // ---- split A into hi/lo bf16, packed 2/word ----
        unsigned h[8], l[8];
#define SPLIT4(v, hA, hB, lA, lB)                                              \
        {                                                                      \
            unsigned short h0_ = bf_hi(v.x), h1_ = bf_hi(v.y);                 \
            unsigned short h2_ = bf_hi(v.z), h3_ = bf_hi(v.w);                 \
            unsigned short l0_ = bf_hi(v.x - bf_f(h0_));                       \
            unsigned short l1_ = bf_hi(v.y - bf_f(h1_));                       \
            unsigned short l2_ = bf_hi(v.z - bf_f(h2_));                       \
            unsigned short l3_ = bf_hi(v.w - bf_f(h3_));                       \
            hA = (unsigned)h0_ | ((unsigned)h1_ << 16);                        \
            hB = (unsigned)h2_ | ((unsigned)h3_ << 16);                        \
            lA = (unsigned)l0_ | ((unsigned)l1_ << 16);                        \
            lB = (unsigned)l2_ | ((unsigned)l3_ << 16);                        \
        }
        SPLIT4(a0, h[0], h[1], l[0], l[1]);
        SPLIT4(a1, h[2], h[3], l[2], l[3]);
        SPLIT4(a2, h[4], h[5], l[4], l[5]);
        SPLIT4(a3, h[6], h[7], l[6], l[7]);
#undef SPLIT4

        __syncthreads();   // previous iteration done reading LDS
        int4* dAH = (int4*)&AsHi[srow * LDT + shalf];
        int4* dAL = (int4*)&AsLo[srow * LDT + shalf];
        dAH[0] = make_int4((int)h[0], (int)h[1], (int)h[2], (int)h[3]);
        dAH[1] = make_int4((int)h[4], (int)h[5], (int)h[6], (int)h[7]);
        dAL[0] = make_int4((int)l[0], (int)l[1], (int)l[2], (int)l[3]);
        dAL[1] = make_int4((int)l[4], (int)l[5], (int)l[6], (int)l[7]);
        int4* dBH = (int4*)&BsHi[srow * LDT + shalf];
        int4* dBL = (int4*)&BsLo[srow * LDT + shalf];
        dBH[0] = wh0; dBH[1] = wh1;
        dBL[0] = wl0; dBL[1] = wl1;
        __syncthreads();

        // ---- fragments + MFMA ----
        short8v bh[4], bl[4];
#pragma unroll
        for (int ni = 0; ni < 4; ++ni) {
            int nrow = wn + ni * 16 + l15;
            bh[ni] = *(const short8v*)&BsHi[nrow * LDT + koff];
            bl[ni] = *(const short8v*)&BsLo[nrow * LDT + koff];
        }
#pragma unroll
        for (int mi = 0; mi < 4; ++mi) {
            int mrow = wm + mi * 16 + l15;
            short8v ah = *(const short8v*)&AsHi[mrow * LDT + koff];
            short8v al = *(const short8v*)&AsLo[mrow * LDT + koff];
#pragma unroll
            for (int ni = 0; ni < 4; ++ni) {
                acc[mi][ni] = __builtin_amdgcn_mfma_f32_16x16x32_bf16(ah, bh[ni], acc[mi][ni], 0, 0, 0);
                acc[mi][ni] = __builtin_amdgcn_mfma_f32_16x16x32_bf16(ah, bl[ni], acc[mi][ni], 0, 0, 0);
                acc[mi][ni] = __builtin_amdgcn_mfma_f32_16x16x32_bf16(al, bh[ni], acc[mi][ni], 0, 0, 0);
            }
        }
    }

    // ---- epilogue: C[row][col] = acc * dinv[row];  row=(lane>>4)*4+i space, col=lane&15
#pragma unroll
    for (int mi = 0; mi < 4; ++mi) {
#pragma unroll
        for (int i = 0; i < 4; ++i) {
            int row = R0 + wm + mi * 16 + (lane >> 4) * 4 + i;
            float sc = rowscale[row];
#pragma unroll
            for (int ni = 0; ni < 4; ++ni) {
                int col = n0 + wn + ni * 16 + l15;
                Out[(size_t)row * N + col] = acc[mi][ni][i] * sc;
            }
        }
    }
}

// ---------------- f32 GEMM (fc1/fc2 only): Out = A @ W + bias ----------------
template <int K, int N, bool HAS_BIAS>
__global__ __launch_bounds__(256) void gemm_kernel(const float* __restrict__ A,
                                                   const float* __restrict__ W,
                                                   const float* __restrict__ bias,
                                                   float* __restrict__ Out) {
    constexpr int BM = 32, KT = 32;
    constexpr int NQ = N / 4;
    constexpr int NG = 256 / NQ;
    constexpr int R  = BM / NG;
    __shared__ float As[BM][KT];
    __shared__ float Ws[KT][N];
    const int tid = threadIdx.x;
    const int q = tid % NQ, g = tid / NQ;
    const int brow = blockIdx.x * BM;

    float acc[R][4];
#pragma unroll
    for (int r = 0; r < R; ++r) {
        if (HAS_BIAS) {
            acc[r][0] = bias[4 * q + 0]; acc[r][1] = bias[4 * q + 1];
            acc[r][2] = bias[4 * q + 2]; acc[r][3] = bias[4 * q + 3];
        } else {
            acc[r][0] = acc[r][1] = acc[r][2] = acc[r][3] = 0.f;
        }
    }

    for (int k0 = 0; k0 < K; k0 += KT) {
        {
            int row = tid >> 3, kq = tid & 7;
            *(float4*)&As[row][4 * kq] =
                *(const float4*)&A[(size_t)(brow + row) * K + k0 + 4 * kq];
        }
#pragma unroll
        for (int i = 0; i < KT * NQ / 256; ++i) {
            int p = tid + 256 * i;
            int kr = p / NQ, c4 = p % NQ;
            *(float4*)&Ws[kr][4 * c4] =
                *(const float4*)&W[(size_t)(k0 + kr) * N + 4 * c4];
        }
        __syncthreads();
#pragma unroll
        for (int kk4 = 0; kk4 < KT / 4; ++kk4) {
            float4 av[R];
#pragma unroll
            for (int r = 0; r < R; ++r)
                av[r] = *(float4*)&As[g + NG * r][4 * kk4];
#pragma unroll
            for (int j = 0; j < 4; ++j) {
                float4 wv = *(float4*)&Ws[4 * kk4 + j][4 * q];
#pragma unroll
                for (int r = 0; r < R; ++r) {
                    float a = (j == 0) ? av[r].x : (j == 1) ? av[r].y
                              : (j == 2) ? av[r].z : av[r].w;
                    acc[r][0] += a * wv.x; acc[r][1] += a * wv.y;
                    acc[r][2] += a * wv.z; acc[r][3] += a * wv.w;
                }
            }
        }
        __syncthreads();
    }
#pragma unroll
    for (int r = 0; r < R; ++r)
        *(float4*)&Out[(size_t)(brow + g + NG * r) * N + 4 * q] = *(float4*)&acc[r][0];
}

// ---------------- gather aggregation (no atomics) ----------------
__global__ __launch_bounds__(256) void gather256_kernel(const float* __restrict__ h,
                                                        const float* __restrict__ bias,
                                                        const float* __restrict__ dinv,
                                                        const int* __restrict__ rowptr,
                                                        const int* __restrict__ csr_src,
                                                        float* __restrict__ out) {
    int wid = threadIdx.x >> 6, lane = threadIdx.x & 63;
    int r = blockIdx.x * 4 + wid;
    if (r >= NN) return;
    int beg = rowptr[r], end = rowptr[r + 1];
    float dr = dinv[r];
    float4 acc = ((const float4*)(h + (size_t)r * 256))[lane];
    for (int k = beg; k < end; ++k) {
        int s = csr_src[k];
        float4 v = ((const float4*)(h + (size_t)s * 256))[lane];
        acc.x += v.x; acc.y += v.y; acc.z += v.z; acc.w += v.w;
    }
    float4 b = ((const float4*)bias)[lane];
    float4 o;
    o.x = b.x + dr * acc.x; o.y = b.y + dr * acc.y;
    o.z = b.z + dr * acc.z; o.w = b.w + dr * acc.w;
    ((float4*)(out + (size_t)r * 256))[lane] = o;
}

__global__ __launch_bounds__(256) void gather128_kernel(const float* __restrict__ h,
                                                        const float* __restrict__ bias,
                                                        const float* __restrict__ dinv,
                                                        const int* __restrict__ rowptr,
                                                        const int* __restrict__ csr_src,
                                                        float* __restrict__ out) {
    int sub = threadIdx.x >> 5, lane = threadIdx.x & 31;
    int r = blockIdx.x * 8 + sub;
    if (r >= NN) return;
    int beg = rowptr[r], end = rowptr[r + 1];
    float dr = dinv[r];
    float4 acc = ((const float4*)(h + (size_t)r * 128))[lane];
    for (int k = beg; k < end; ++k) {
        int s = csr_src[k];
        float4 v = ((const float4*)(h + (size_t)s * 128))[lane];
        acc.x += v.x; acc.y += v.y; acc.z += v.z; acc.w += v.w;
    }
    float4 b = ((const float4*)bias)[lane];
    float4 o;
    o.x = b.x + dr * acc.x; o.y = b.y + dr * acc.y;
    o.z = b.z + dr * acc.z; o.w = b.w + dr * acc.w;
    ((float4*)(out + (size_t)r * 128))[lane] = o;
}

// ---------------- BN stats / finalize / apply+relu ----------------
__global__ void bn_stats_kernel(const float* __restrict__ a, float* __restrict__ sums,
                                float* __restrict__ sumsq) {
    int c = threadIdx.x;
    float s = 0.f, s2 = 0.f;
    for (int row = blockIdx.x; row < NN; row += gridDim.x) {
        float v = a[(size_t)row * 256 + c];
        s += v; s2 += v * v;
    }
    atomicAdd(&sums[c], s);
    atomicAdd(&sumsq[c], s2);
}

__global__ void bn_final_kernel(const float* __restrict__ sums, const float* __restrict__ sumsq,
                                const float* __restrict__ gamma, const float* __restrict__ beta,
                                float* __restrict__ scale, float* __restrict__ shift) {
    int c = threadIdx.x;
    const float Nf = (float)NN;
    float mean = sums[c] / Nf;
    float var = sumsq[c] / Nf - mean * mean;
    float sc = gamma[c] * rsqrtf(var + BN_EPS);
    scale[c] = sc;
    shift[c] = beta[c] - mean * sc;
}

__global__ void bn_apply_relu_kernel(float* __restrict__ a, const float* __restrict__ scale,
                                     const float* __restrict__ shift) {
    int stride = gridDim.x * blockDim.x;
    for (int idx = blockIdx.x * blockDim.x + threadIdx.x; idx < NN * 64; idx += stride) {
        int qq = idx & 63;
        float4 v = *(float4*)&a[(size_t)idx * 4];
        float4 sc = *(const float4*)&scale[4 * qq];
        float4 sh = *(const float4*)&shift[4 * qq];
        v.x = fmaxf(v.x * sc.x + sh.x, 0.f);
        v.y = fmaxf(v.y * sc.y + sh.y, 0.f);
        v.z = fmaxf(v.z * sc.z + sh.z, 0.f);
        v.w = fmaxf(v.w * sc.w + sh.w, 0.f);
        *(float4*)&a[(size_t)idx * 4] = v;
    }
}

extern "C" void kernel_launch(void* const* d_in, const int* in_sizes, int n_in,
                              void* d_out, int out_size, void* d_ws, size_t ws_size,
                              hipStream_t stream) {
    const float* x       = (const float*)d_in[0];
    const float* y       = (const float*)d_in[1];
    const void*  ei      = d_in[2];
    const float* fc1_w   = (const float*)d_in[3];
    const float* fc1_b   = (const float*)d_in[4];
    const float* fc2_w   = (const float*)d_in[5];
    const float* fc2_b   = (const float*)d_in[6];
    const float* conv1_w = (const float*)d_in[7];
    const float* conv1_b = (const float*)d_in[8];
    const float* conv2_w = (const float*)d_in[9];
    const float* conv2_b = (const float*)d_in[10];
    const float* gamma   = (const float*)d_in[11];
    const float* beta    = (const float*)d_in[12];
    float* out = (float*)d_out;

    float* ws = (float*)d_ws;
    float* bufA = ws;                       // NN*256: z0, then a1
    float* bufB = ws + (size_t)NN * 256;    // NN*256: h1', then h2'
    float* aux  = bufB + (size_t)NN * 256;
    float* dinv  = aux;                      // NN
    float* sums  = dinv + NN;                // 256
    float* sumsq = sums + 256;               // 256
    float* scale = sumsq + 256;              // 256
    float* shift = scale + 256;              // 256
    int*   flag      = (int*)(shift + 256);  // 1
    int*   cnt       = flag + 1;             // NN
    int*   rowptr    = cnt + NN;             // NN+1
    int*   cursor    = rowptr + NN + 1;      // NN
    int*   blockSums = cursor + NN;          // NB_SCAN
    int*   csr_src   = blockSums + NB_SCAN + 3;  // EE
    // 16B-aligned W^T split buffers after csr
    short* w1th = (short*)(((uintptr_t)(csr_src + EE) + 15) & ~(uintptr_t)15);
    short* w1tl = w1th + 256 * 256;
    short* w2th = w1tl + 256 * 256;
    short* w2tl = w2th + 256 * 128;

    // ---- CSR build + W split ----
    prep_kernel<<<320, 256, 0, stream>>>((const int*)ei, cnt, cursor, rowptr, sums, sumsq, flag);
    hist_kernel<<<1024, 256, 0, stream>>>(ei, flag, cnt);
    dinv_kernel<<<(NN + 255) / 256, 256, 0, stream>>>(cnt, dinv);
    scan1_kernel<<<NB_SCAN, 256, 0, stream>>>(cnt, rowptr, blockSums);
    scan2_kernel<<<1, 512, 0, stream>>>(blockSums);
    scan3_kernel<<<NB_SCAN, 256, 0, stream>>>(rowptr, blockSums);
    fill_kernel<<<1024, 256, 0, stream>>>(ei, flag, rowptr, cursor, csr_src);
    wsplit_kernel<<<256, 256, 0, stream>>>(conv1_w, conv2_w, w1th, w1tl, w2th, w2tl);

    // ---- input projections -> z0 in bufA (fp32 path, ragged M) ----
    gemm_kernel<64, 256, true><<<N_U / 32, 256, 0, stream>>>(x, fc1_w, fc1_b, bufA);
    gemm_kernel<128, 256, true><<<N_M / 32, 256, 0, stream>>>(y, fc2_w, fc2_b,
                                                              bufA + (size_t)N_U * 256);
    // ---- conv1: h1' = (z0 @ W1) * dinv[row] -> bufB (split-bf16 MFMA); gather -> bufA
    mfma_gemm_kernel<256, 256><<<dim3(625, 2), 256, 0, stream>>>(bufA, w1th, w1tl, dinv, bufB);
    gather256_kernel<<<NN / 4, 256, 0, stream>>>(bufB, conv1_b, dinv, rowptr, csr_src, bufA);

    // ---- BN + ReLU in place on bufA ----
    bn_stats_kernel<<<256, 256, 0, stream>>>(bufA, sums, sumsq);
    bn_final_kernel<<<1, 256, 0, stream>>>(sums, sumsq, gamma, beta, scale, shift);
    bn_apply_relu_kernel<<<2048, 256, 0, stream>>>(bufA, scale, shift);

    // ---- conv2: h2' = (a1 @ W2) * dinv[row] -> bufB (split-bf16 MFMA); gather -> out
    mfma_gemm_kernel<256, 128><<<dim3(625, 1), 256, 0, stream>>>(bufA, w2th, w2tl, dinv, bufB);
    gather128_kernel<<<NN / 8, 256, 0, stream>>>(bufB, conv2_b, dinv, rowptr, csr_src, out);
}

// Round 6
// 503.874 us; speedup vs baseline: 6.0223x; 1.0867x over previous
//
#include <hip/hip_runtime.h>
#include <math.h>
#include <stdint.h>

#define N_U 60000
#define N_M 20000
#define NN  80000
#define EE  500000
#define BN_EPS 1e-5f
#define NB_SCAN 313   // ceil(80000/256)

typedef __attribute__((ext_vector_type(8))) short short8v;   // 8 bf16 = 4 VGPR (MFMA A/B frag)
typedef __attribute__((ext_vector_type(4))) float f32x4;     // MFMA C/D frag

// ---------------- bf16 split helpers ----------------
__device__ __forceinline__ unsigned short bf_hi(float f) {
    unsigned u = __float_as_uint(f);
    return (unsigned short)((u + 0x7FFFu + ((u >> 16) & 1u)) >> 16);   // RNE
}
__device__ __forceinline__ float bf_f(unsigned short h) {
    return __uint_as_float(((unsigned)h) << 16);
}

// ---------------- prep: zero cnt/cursor/BN stats, rowptr[NN]=EE, detect edge dtype ----
__global__ void prep_kernel(const int* __restrict__ ei32, int* __restrict__ cnt,
                            int* __restrict__ cursor, int* __restrict__ rowptr,
                            float* __restrict__ sums, float* __restrict__ sumsq,
                            int* __restrict__ flag) {
    int i = blockIdx.x * blockDim.x + threadIdx.x;
    if (i < 256) { sums[i] = 0.f; sumsq[i] = 0.f; }
    for (int j = i; j < NN; j += gridDim.x * blockDim.x) { cnt[j] = 0; cursor[j] = 0; }
    if (i == 0) rowptr[NN] = EE;
    if (blockIdx.x == 0) {
        __shared__ int nz;
        if (threadIdx.x == 0) nz = 0;
        __syncthreads();
        int v = ei32[2 * threadIdx.x + 1];
        if (v != 0) atomicOr(&nz, 1);
        __syncthreads();
        if (threadIdx.x == 0) *flag = (nz == 0) ? 1 : 0;  // 1 -> int64
    }
}

__device__ __forceinline__ int load_idx(const void* ei, int f, int pos) {
    return f ? (int)((const long long*)ei)[pos] : ((const int*)ei)[pos];
}

// ---------------- degree histogram (dst side, edges only) ----------------
__global__ void hist_kernel(const void* __restrict__ ei, const int* __restrict__ flag,
                            int* __restrict__ cnt) {
    int f = *flag;
    int stride = gridDim.x * blockDim.x;
    for (int e = blockIdx.x * blockDim.x + threadIdx.x; e < EE; e += stride) {
        int d = load_idx(ei, f, EE + e);
        atomicAdd(&cnt[d], 1);
    }
}

__global__ void dinv_kernel(const int* __restrict__ cnt, float* __restrict__ dinv) {
    int i = blockIdx.x * blockDim.x + threadIdx.x;
    if (i < NN) dinv[i] = rsqrtf(1.0f + (float)cnt[i]);   // +1 self-loop
}

// ---------------- exclusive scan of cnt -> rowptr (3 kernels) ----------------
__global__ void scan1_kernel(const int* __restrict__ cnt, int* __restrict__ rowptr,
                             int* __restrict__ blockSums) {
    __shared__ int sh[256];
    int tid = threadIdx.x;
    int i = blockIdx.x * 256 + tid;
    int v = (i < NN) ? cnt[i] : 0;
    int x = v;
    sh[tid] = x; __syncthreads();
#pragma unroll
    for (int off = 1; off < 256; off <<= 1) {
        int t = (tid >= off) ? sh[tid - off] : 0;
        __syncthreads();
        x += t; sh[tid] = x;
        __syncthreads();
    }
    if (i < NN) rowptr[i] = x - v;
    if (tid == 255) blockSums[blockIdx.x] = x;
}

__global__ void scan2_kernel(int* __restrict__ blockSums) {
    __shared__ int sh[512];
    int tid = threadIdx.x;
    int v = (tid < NB_SCAN) ? blockSums[tid] : 0;
    int x = v;
    sh[tid] = x; __syncthreads();
#pragma unroll
    for (int off = 1; off < 512; off <<= 1) {
        int t = (tid >= off) ? sh[tid - off] : 0;
        __syncthreads();
        x += t; sh[tid] = x;
        __syncthreads();
    }
    if (tid < NB_SCAN) blockSums[tid] = x - v;
}

__global__ void scan3_kernel(int* __restrict__ rowptr, const int* __restrict__ blockSums) {
    int i = blockIdx.x * 256 + threadIdx.x;
    if (i < NN) rowptr[i] += blockSums[blockIdx.x];
}

// ---------------- CSR fill: csr_src grouped by dst ----------------
__global__ void fill_kernel(const void* __restrict__ ei, const int* __restrict__ flag,
                            const int* __restrict__ rowptr, int* __restrict__ cursor,
                            int* __restrict__ csr_src) {
    int f = *flag;
    int stride = gridDim.x * blockDim.x;
    for (int e = blockIdx.x * blockDim.x + threadIdx.x; e < EE; e += stride) {
        int s = load_idx(ei, f, e);
        int d = load_idx(ei, f, EE + e);
        int pos = rowptr[d] + atomicAdd(&cursor[d], 1);
        csr_src[pos] = s;
    }
}

// ---------------- all-W transpose + bf16 split (once per launch, tiny) ----------------
// W[K][N] f32 row-major -> Wt_hi/Wt_lo [N][K] bf16; covers conv1/conv2/fc1/fc2
__global__ void wsplit_kernel(const float* __restrict__ W1, const float* __restrict__ W2,
                              const float* __restrict__ Wf1, const float* __restrict__ Wf2,
                              short* __restrict__ W1tHi, short* __restrict__ W1tLo,
                              short* __restrict__ W2tHi, short* __restrict__ W2tLo,
                              short* __restrict__ Wf1tHi, short* __restrict__ Wf1tLo,
                              short* __restrict__ Wf2tHi, short* __restrict__ Wf2tLo) {
    int i = blockIdx.x * 256 + threadIdx.x;   // grid covers 65536
    if (i < 256 * 256) {          // conv1: K=256, N=256
        int k = i >> 8, n = i & 255;
        float v = W1[i];
        unsigned short h = bf_hi(v);
        unsigned short l = bf_hi(v - bf_f(h));
        W1tHi[n * 256 + k] = (short)h;
        W1tLo[n * 256 + k] = (short)l;
    }
    if (i < 256 * 128) {          // conv2: K=256, N=128
        int k = i >> 7, n = i & 127;
        float v = W2[i];
        unsigned short h = bf_hi(v);
        unsigned short l = bf_hi(v - bf_f(h));
        W2tHi[n * 256 + k] = (short)h;
        W2tLo[n * 256 + k] = (short)l;
    }
    if (i < 64 * 256) {           // fc1: K=64, N=256
        int k = i >> 8, n = i & 255;
        float v = Wf1[i];
        unsigned short h = bf_hi(v);
        unsigned short l = bf_hi(v - bf_f(h));
        Wf1tHi[n * 64 + k] = (short)h;
        Wf1tLo[n * 64 + k] = (short)l;
    }
    if (i < 128 * 256) {          // fc2: K=128, N=256
        int k = i >> 8, n = i & 255;
        float v = Wf2[i];
        unsigned short h = bf_hi(v);
        unsigned short l = bf_hi(v - bf_f(h));
        Wf2tHi[n * 128 + k] = (short)h;
        Wf2tLo[n * 128 + k] = (short)l;
    }
}

// ---------------- split-bf16 MFMA GEMM ----------
// Block: 256 thr (4 waves, 2x2 of 64x64), tile 128x128, BK=32.
// A[M][K] f32 split to bf16 hi/lo in-kernel; W pre-split transposed [N][K] bf16.
// MODE 0: Out = (A@W) * rowscale[row]   (ep = rowscale)
// MODE 1: Out = (A@W) + bias[col]       (ep = bias), M may be ragged (guarded)
// BNRELU: A-path applies a = max(a*bnsc[k]+bnsh[k], 0) before split (exact f32, as
//         the standalone bn_apply pass did).
template <int K, int N, int MODE, bool BNRELU>
__global__ __launch_bounds__(256) void mfma_gemm_kernel(
    int M, const float* __restrict__ A, const short* __restrict__ WtHi,
    const short* __restrict__ WtLo, const float* __restrict__ ep,
    const float* __restrict__ bnsc, const float* __restrict__ bnsh,
    float* __restrict__ Out) {
    constexpr int LDT = 40;   // padded LDS row stride (bf16): 80 B = 20 banks -> 2-way max
    __shared__ short AsHi[128 * LDT];
    __shared__ short AsLo[128 * LDT];
    __shared__ short BsHi[128 * LDT];
    __shared__ short BsLo[128 * LDT];
    const int tid  = threadIdx.x;
    const int lane = tid & 63, wave = tid >> 6;
    const int wm = (wave >> 1) * 64, wn = (wave & 1) * 64;
    const int R0 = blockIdx.x * 128;
    const int n0 = blockIdx.y * 128;
    const int srow  = tid >> 1;          // staging row 0..127 (2 thr/row)
    const int shalf = (tid & 1) * 16;    // element offset 0 / 16
    const int l15  = lane & 15;
    const int koff = (lane >> 4) * 8;    // k-slice base per lane

    f32x4 acc[4][4];
#pragma unroll
    for (int mi = 0; mi < 4; ++mi)
#pragma unroll
        for (int ni = 0; ni < 4; ++ni)
            acc[mi][ni] = (f32x4){0.f, 0.f, 0.f, 0.f};

    const int arow = min(R0 + srow, M - 1);   // clamp for ragged tail (loads only)

    for (int k0 = 0; k0 < K; k0 += 32) {
        // ---- global loads ----
        const float4* ga = (const float4*)&A[(size_t)arow * K + k0 + shalf];
        float4 a0 = ga[0], a1 = ga[1], a2 = ga[2], a3 = ga[3];
        const int4* gwh = (const int4*)&WtHi[(size_t)(n0 + srow) * K + k0 + shalf];
        const int4* gwl = (const int4*)&WtLo[(size_t)(n0 + srow) * K + k0 + shalf];
        int4 wh0 = gwh[0], wh1 = gwh[1];
        int4 wl0 = gwl[0], wl1 = gwl[1];

        if (BNRELU) {   // fused BN-apply + ReLU on A (per-channel k)
            const float4* gs = (const float4*)&bnsc[k0 + shalf];
            const float4* gh = (const float4*)&bnsh[k0 + shalf];
            float4 s0 = gs[0], s1 = gs[1], s2 = gs[2], s3 = gs[3];
            float4 t0 = gh[0], t1 = gh[1], t2 = gh[2], t3 = gh[3];
#define BNR4(a, s, t)                                                          \
            a.x = fmaxf(a.x * s.x + t.x, 0.f);                                 \
            a.y = fmaxf(a.y * s.y + t.y, 0.f);                                 \
            a.z = fmaxf(a.z * s.z + t.z, 0.f);                                 \
            a.w = fmaxf(a.w * s.w + t.w, 0.f);
            BNR4(a0, s0, t0); BNR4(a1, s1, t1); BNR4(a2, s2, t2); BNR4(a3, s3, t3);
#undef BNR4
        }

        // ---- split A into hi/lo bf16, packed 2/word ----
        unsigned h[8], l[8];
#define SPLIT4(v, hA, hB, lA, lB)                                              \
        {                                                                      \
            unsigned short h0_ = bf_hi(v.x), h1_ = bf_hi(v.y);                 \
            unsigned short h2_ = bf_hi(v.z), h3_ = bf_hi(v.w);                 \
            unsigned short l0_ = bf_hi(v.x - bf_f(h0_));                       \
            unsigned short l1_ = bf_hi(v.y - bf_f(h1_));                       \
            unsigned short l2_ = bf_hi(v.z - bf_f(h2_));                       \
            unsigned short l3_ = bf_hi(v.w - bf_f(h3_));                       \
            hA = (unsigned)h0_ | ((unsigned)h1_ << 16);                        \
            hB = (unsigned)h2_ | ((unsigned)h3_ << 16);                        \
            lA = (unsigned)l0_ | ((unsigned)l1_ << 16);                        \
            lB = (unsigned)l2_ | ((unsigned)l3_ << 16);                        \
        }
        SPLIT4(a0, h[0], h[1], l[0], l[1]);
        SPLIT4(a1, h[2], h[3], l[2], l[3]);
        SPLIT4(a2, h[4], h[5], l[4], l[5]);
        SPLIT4(a3, h[6], h[7], l[6], l[7]);
#undef SPLIT4

        __syncthreads();   // previous iteration done reading LDS
        int4* dAH = (int4*)&AsHi[srow * LDT + shalf];
        int4* dAL = (int4*)&AsLo[srow * LDT + shalf];
        dAH[0] = make_int4((int)h[0], (int)h[1], (int)h[2], (int)h[3]);
        dAH[1] = make_int4((int)h[4], (int)h[5], (int)h[6], (int)h[7]);
        dAL[0] = make_int4((int)l[0], (int)l[1], (int)l[2], (int)l[3]);
        dAL[1] = make_int4((int)l[4], (int)l[5], (int)l[6], (int)l[7]);
        int4* dBH = (int4*)&BsHi[srow * LDT + shalf];
        int4* dBL = (int4*)&BsLo[srow * LDT + shalf];
        dBH[0] = wh0; dBH[1] = wh1;
        dBL[0] = wl0; dBL[1] = wl1;
        __syncthreads();

        // ---- fragments + MFMA (AhWh + AhWl + AlWh; fp32 accum) ----
        short8v bh[4], bl[4];
#pragma unroll
        for (int ni = 0; ni < 4; ++ni) {
            int nrow = wn + ni * 16 + l15;
            bh[ni] = *(const short8v*)&BsHi[nrow * LDT + koff];
            bl[ni] = *(const short8v*)&BsLo[nrow * LDT + koff];
        }
#pragma unroll
        for (int mi = 0; mi < 4; ++mi) {
            int mrow = wm + mi * 16 + l15;
            short8v ah = *(const short8v*)&AsHi[mrow * LDT + koff];
            short8v al = *(const short8v*)&AsLo[mrow * LDT + koff];
#pragma unroll
            for (int ni = 0; ni < 4; ++ni) {
                acc[mi][ni] = __builtin_amdgcn_mfma_f32_16x16x32_bf16(ah, bh[ni], acc[mi][ni], 0, 0, 0);
                acc[mi][ni] = __builtin_amdgcn_mfma_f32_16x16x32_bf16(ah, bl[ni], acc[mi][ni], 0, 0, 0);
                acc[mi][ni] = __builtin_amdgcn_mfma_f32_16x16x32_bf16(al, bh[ni], acc[mi][ni], 0, 0, 0);
            }
        }
    }

    // ---- epilogue: C/D layout col=lane&15, row=(lane>>4)*4+i ----
#pragma unroll
    for (int mi = 0; mi < 4; ++mi) {
#pragma unroll
        for (int i = 0; i < 4; ++i) {
            int row = R0 + wm + mi * 16 + (lane >> 4) * 4 + i;
            if (row < M) {
                float sc = (MODE == 0) ? ep[row] : 1.0f;
#pragma unroll
                for (int ni = 0; ni < 4; ++ni) {
                    int col = n0 + wn + ni * 16 + l15;
                    float v = acc[mi][ni][i];
                    v = (MODE == 0) ? v * sc : v + ep[col];
                    Out[(size_t)row * N + col] = v;
                }
            }
        }
    }
}

// ---------------- gather aggregation (no atomics, 4-way MLP batched) ----------------
// h pre-scaled by dinv[row]:  out[d] = bias + dinv[d]*( h'[d] + sum_{s in N(d)} h'[s] )
__global__ __launch_bounds__(256) void gather256_kernel(const float* __restrict__ h,
                                                        const float* __restrict__ bias,
                                                        const float* __restrict__ dinv,
                                                        const int* __restrict__ rowptr,
                                                        const int* __restrict__ csr_src,
                                                        float* __restrict__ out) {
    int wid = threadIdx.x >> 6, lane = threadIdx.x & 63;
    int r = blockIdx.x * 4 + wid;
    if (r >= NN) return;
    int beg = rowptr[r], end = rowptr[r + 1];
    float dr = dinv[r];
    float4 acc = ((const float4*)(h + (size_t)r * 256))[lane];
    int k = beg;
    for (; k + 3 < end; k += 4) {     // batch: 4 independent row loads in flight
        int s0 = csr_src[k], s1 = csr_src[k + 1], s2 = csr_src[k + 2], s3 = csr_src[k + 3];
        float4 v0 = ((const float4*)(h + (size_t)s0 * 256))[lane];
        float4 v1 = ((const float4*)(h + (size_t)s1 * 256))[lane];
        float4 v2 = ((const float4*)(h + (size_t)s2 * 256))[lane];
        float4 v3 = ((const float4*)(h + (size_t)s3 * 256))[lane];
        acc.x += v0.x; acc.y += v0.y; acc.z += v0.z; acc.w += v0.w;
        acc.x += v1.x; acc.y += v1.y; acc.z += v1.z; acc.w += v1.w;
        acc.x += v2.x; acc.y += v2.y; acc.z += v2.z; acc.w += v2.w;
        acc.x += v3.x; acc.y += v3.y; acc.z += v3.z; acc.w += v3.w;
    }
    for (; k < end; ++k) {
        int s = csr_src[k];
        float4 v = ((const float4*)(h + (size_t)s * 256))[lane];
        acc.x += v.x; acc.y += v.y; acc.z += v.z; acc.w += v.w;
    }
    float4 b = ((const float4*)bias)[lane];
    float4 o;
    o.x = b.x + dr * acc.x; o.y = b.y + dr * acc.y;
    o.z = b.z + dr * acc.z; o.w = b.w + dr * acc.w;
    ((float4*)(out + (size_t)r * 256))[lane] = o;
}

__global__ __launch_bounds__(256) void gather128_kernel(const float* __restrict__ h,
                                                        const float* __restrict__ bias,
                                                        const float* __restrict__ dinv,
                                                        const int* __restrict__ rowptr,
                                                        const int* __restrict__ csr_src,
                                                        float* __restrict__ out) {
    int sub = threadIdx.x >> 5, lane = threadIdx.x & 31;
    int r = blockIdx.x * 8 + sub;
    if (r >= NN) return;
    int beg = rowptr[r], end = rowptr[r + 1];
    float dr = dinv[r];
    float4 acc = ((const float4*)(h + (size_t)r * 128))[lane];
    int k = beg;
    for (; k + 3 < end; k += 4) {
        int s0 = csr_src[k], s1 = csr_src[k + 1], s2 = csr_src[k + 2], s3 = csr_src[k + 3];
        float4 v0 = ((const float4*)(h + (size_t)s0 * 128))[lane];
        float4 v1 = ((const float4*)(h + (size_t)s1 * 128))[lane];
        float4 v2 = ((const float4*)(h + (size_t)s2 * 128))[lane];
        float4 v3 = ((const float4*)(h + (size_t)s3 * 128))[lane];
        acc.x += v0.x; acc.y += v0.y; acc.z += v0.z; acc.w += v0.w;
        acc.x += v1.x; acc.y += v1.y; acc.z += v1.z; acc.w += v1.w;
        acc.x += v2.x; acc.y += v2.y; acc.z += v2.z; acc.w += v2.w;
        acc.x += v3.x; acc.y += v3.y; acc.z += v3.z; acc.w += v3.w;
    }
    for (; k < end; ++k) {
        int s = csr_src[k];
        float4 v = ((const float4*)(h + (size_t)s * 128))[lane];
        acc.x += v.x; acc.y += v.y; acc.z += v.z; acc.w += v.w;
    }
    float4 b = ((const float4*)bias)[lane];
    float4 o;
    o.x = b.x + dr * acc.x; o.y = b.y + dr * acc.y;
    o.z = b.z + dr * acc.z; o.w = b.w + dr * acc.w;
    ((float4*)(out + (size_t)r * 128))[lane] = o;
}

// ---------------- BN stats / finalize ----------------
__global__ void bn_stats_kernel(const float* __restrict__ a, float* __restrict__ sums,
                                float* __restrict__ sumsq) {
    int c = threadIdx.x;
    float s = 0.f, s2 = 0.f;
    for (int row = blockIdx.x; row < NN; row += gridDim.x) {
        float v = a[(size_t)row * 256 + c];
        s += v; s2 += v * v;
    }
    atomicAdd(&sums[c], s);
    atomicAdd(&sumsq[c], s2);
}

__global__ void bn_final_kernel(const float* __restrict__ sums, const float* __restrict__ sumsq,
                                const float* __restrict__ gamma, const float* __restrict__ beta,
                                float* __restrict__ scale, float* __restrict__ shift) {
    int c = threadIdx.x;
    const float Nf = (float)NN;
    float mean = sums[c] / Nf;
    float var = sumsq[c] / Nf - mean * mean;
    float sc = gamma[c] * rsqrtf(var + BN_EPS);
    scale[c] = sc;
    shift[c] = beta[c] - mean * sc;
}

extern "C" void kernel_launch(void* const* d_in, const int* in_sizes, int n_in,
                              void* d_out, int out_size, void* d_ws, size_t ws_size,
                              hipStream_t stream) {
    const float* x       = (const float*)d_in[0];
    const float* y       = (const float*)d_in[1];
    const void*  ei      = d_in[2];
    const float* fc1_w   = (const float*)d_in[3];
    const float* fc1_b   = (const float*)d_in[4];
    const float* fc2_w   = (const float*)d_in[5];
    const float* fc2_b   = (const float*)d_in[6];
    const float* conv1_w = (const float*)d_in[7];
    const float* conv1_b = (const float*)d_in[8];
    const float* conv2_w = (const float*)d_in[9];
    const float* conv2_b = (const float*)d_in[10];
    const float* gamma   = (const float*)d_in[11];
    const float* beta    = (const float*)d_in[12];
    float* out = (float*)d_out;

    float* ws = (float*)d_ws;
    float* bufA = ws;                       // NN*256: z0, then a1(raw gather out)
    float* bufB = ws + (size_t)NN * 256;    // NN*256: h1', then h2'
    float* aux  = bufB + (size_t)NN * 256;
    float* dinv  = aux;                      // NN
    float* sums  = dinv + NN;                // 256
    float* sumsq = sums + 256;               // 256
    float* scale = sumsq + 256;              // 256
    float* shift = scale + 256;              // 256
    int*   flag      = (int*)(shift + 256);  // 1
    int*   cnt       = flag + 1;             // NN
    int*   rowptr    = cnt + NN;             // NN+1
    int*   cursor    = rowptr + NN + 1;      // NN
    int*   blockSums = cursor + NN;          // NB_SCAN
    int*   csr_src   = blockSums + NB_SCAN + 3;  // EE
    // 16B-aligned W^T split buffers after csr
    short* w1th = (short*)(((uintptr_t)(csr_src + EE) + 15) & ~(uintptr_t)15);
    short* w1tl = w1th + 256 * 256;
    short* w2th = w1tl + 256 * 256;
    short* w2tl = w2th + 256 * 128;
    short* wf1h = w2tl + 256 * 128;
    short* wf1l = wf1h + 256 * 64;
    short* wf2h = wf1l + 256 * 64;
    short* wf2l = wf2h + 256 * 128;

    // ---- CSR build + W split ----
    prep_kernel<<<320, 256, 0, stream>>>((const int*)ei, cnt, cursor, rowptr, sums, sumsq, flag);
    hist_kernel<<<1024, 256, 0, stream>>>(ei, flag, cnt);
    dinv_kernel<<<(NN + 255) / 256, 256, 0, stream>>>(cnt, dinv);
    scan1_kernel<<<NB_SCAN, 256, 0, stream>>>(cnt, rowptr, blockSums);
    scan2_kernel<<<1, 512, 0, stream>>>(blockSums);
    scan3_kernel<<<NB_SCAN, 256, 0, stream>>>(rowptr, blockSums);
    fill_kernel<<<1024, 256, 0, stream>>>(ei, flag, rowptr, cursor, csr_src);
    wsplit_kernel<<<256, 256, 0, stream>>>(conv1_w, conv2_w, fc1_w, fc2_w,
                                           w1th, w1tl, w2th, w2tl, wf1h, wf1l, wf2h, wf2l);

    // ---- input projections -> z0 in bufA (split-bf16 MFMA, ragged M guarded) ----
    mfma_gemm_kernel<64, 256, 1, false><<<dim3(469, 2), 256, 0, stream>>>(
        N_U, x, wf1h, wf1l, fc1_b, nullptr, nullptr, bufA);
    mfma_gemm_kernel<128, 256, 1, false><<<dim3(157, 2), 256, 0, stream>>>(
        N_M, y, wf2h, wf2l, fc2_b, nullptr, nullptr, bufA + (size_t)N_U * 256);

    // ---- conv1: h1' = (z0 @ W1) * dinv[row] -> bufB; gather -> bufA (raw z) ----
    mfma_gemm_kernel<256, 256, 0, false><<<dim3(625, 2), 256, 0, stream>>>(
        NN, bufA, w1th, w1tl, dinv, nullptr, nullptr, bufB);
    gather256_kernel<<<NN / 4, 256, 0, stream>>>(bufB, conv1_b, dinv, rowptr, csr_src, bufA);

    // ---- BN stats on raw z; apply+ReLU fused into conv2's A-path ----
    bn_stats_kernel<<<256, 256, 0, stream>>>(bufA, sums, sumsq);
    bn_final_kernel<<<1, 256, 0, stream>>>(sums, sumsq, gamma, beta, scale, shift);

    // ---- conv2: h2' = (relu(bn(z)) @ W2) * dinv[row] -> bufB; gather -> out ----
    mfma_gemm_kernel<256, 128, 0, true><<<dim3(625, 1), 256, 0, stream>>>(
        NN, bufA, w2th, w2tl, dinv, scale, shift, bufB);
    gather128_kernel<<<NN / 8, 256, 0, stream>>>(bufB, conv2_b, dinv, rowptr, csr_src, out);
}

// Round 7
// 402.522 us; speedup vs baseline: 7.5387x; 1.2518x over previous
//
#include <hip/hip_runtime.h>
#include <math.h>
#include <stdint.h>

#define N_U 60000
#define N_M 20000
#define NN  80000
#define EE  500000
#define BN_EPS 1e-5f
#define NB_SCAN 313   // ceil(80000/256)

typedef __attribute__((ext_vector_type(8))) short short8v;   // 8 bf16 = 4 VGPR (MFMA A/B frag)
typedef __attribute__((ext_vector_type(4))) float f32x4;     // MFMA C/D frag

// ---------------- bf16 helpers ----------------
__device__ __forceinline__ unsigned short bf_hi(float f) {
    unsigned u = __float_as_uint(f);
    return (unsigned short)((u + 0x7FFFu + ((u >> 16) & 1u)) >> 16);   // RNE
}
__device__ __forceinline__ float bf_f(unsigned short h) {
    return __uint_as_float(((unsigned)h) << 16);
}

// ---------------- prep: zero cnt/cursor/BN stats, rowptr[NN]=EE, detect edge dtype ----
__global__ void prep_kernel(const int* __restrict__ ei32, int* __restrict__ cnt,
                            int* __restrict__ cursor, int* __restrict__ rowptr,
                            float* __restrict__ sums, float* __restrict__ sumsq,
                            int* __restrict__ flag) {
    int i = blockIdx.x * blockDim.x + threadIdx.x;
    if (i < 256) { sums[i] = 0.f; sumsq[i] = 0.f; }
    for (int j = i; j < NN; j += gridDim.x * blockDim.x) { cnt[j] = 0; cursor[j] = 0; }
    if (i == 0) rowptr[NN] = EE;
    if (blockIdx.x == 0) {
        __shared__ int nz;
        if (threadIdx.x == 0) nz = 0;
        __syncthreads();
        int v = ei32[2 * threadIdx.x + 1];
        if (v != 0) atomicOr(&nz, 1);
        __syncthreads();
        if (threadIdx.x == 0) *flag = (nz == 0) ? 1 : 0;  // 1 -> int64
    }
}

__device__ __forceinline__ int load_idx(const void* ei, int f, int pos) {
    return f ? (int)((const long long*)ei)[pos] : ((const int*)ei)[pos];
}

// ---------------- degree histogram (dst side, edges only) ----------------
__global__ void hist_kernel(const void* __restrict__ ei, const int* __restrict__ flag,
                            int* __restrict__ cnt) {
    int f = *flag;
    int stride = gridDim.x * blockDim.x;
    for (int e = blockIdx.x * blockDim.x + threadIdx.x; e < EE; e += stride) {
        int d = load_idx(ei, f, EE + e);
        atomicAdd(&cnt[d], 1);
    }
}

__global__ void dinv_kernel(const int* __restrict__ cnt, float* __restrict__ dinv) {
    int i = blockIdx.x * blockDim.x + threadIdx.x;
    if (i < NN) dinv[i] = rsqrtf(1.0f + (float)cnt[i]);   // +1 self-loop
}

// ---------------- exclusive scan of cnt -> rowptr (3 kernels) ----------------
__global__ void scan1_kernel(const int* __restrict__ cnt, int* __restrict__ rowptr,
                             int* __restrict__ blockSums) {
    __shared__ int sh[256];
    int tid = threadIdx.x;
    int i = blockIdx.x * 256 + tid;
    int v = (i < NN) ? cnt[i] : 0;
    int x = v;
    sh[tid] = x; __syncthreads();
#pragma unroll
    for (int off = 1; off < 256; off <<= 1) {
        int t = (tid >= off) ? sh[tid - off] : 0;
        __syncthreads();
        x += t; sh[tid] = x;
        __syncthreads();
    }
    if (i < NN) rowptr[i] = x - v;
    if (tid == 255) blockSums[blockIdx.x] = x;
}

__global__ void scan2_kernel(int* __restrict__ blockSums) {
    __shared__ int sh[512];
    int tid = threadIdx.x;
    int v = (tid < NB_SCAN) ? blockSums[tid] : 0;
    int x = v;
    sh[tid] = x; __syncthreads();
#pragma unroll
    for (int off = 1; off < 512; off <<= 1) {
        int t = (tid >= off) ? sh[tid - off] : 0;
        __syncthreads();
        x += t; sh[tid] = x;
        __syncthreads();
    }
    if (tid < NB_SCAN) blockSums[tid] = x - v;
}

__global__ void scan3_kernel(int* __restrict__ rowptr, const int* __restrict__ blockSums) {
    int i = blockIdx.x * 256 + threadIdx.x;
    if (i < NN) rowptr[i] += blockSums[blockIdx.x];
}

// ---------------- CSR fill: csr_src grouped by dst ----------------
__global__ void fill_kernel(const void* __restrict__ ei, const int* __restrict__ flag,
                            const int* __restrict__ rowptr, int* __restrict__ cursor,
                            int* __restrict__ csr_src) {
    int f = *flag;
    int stride = gridDim.x * blockDim.x;
    for (int e = blockIdx.x * blockDim.x + threadIdx.x; e < EE; e += stride) {
        int s = load_idx(ei, f, e);
        int d = load_idx(ei, f, EE + e);
        int pos = rowptr[d] + atomicAdd(&cursor[d], 1);
        csr_src[pos] = s;
    }
}

// ---------------- all-W transpose + bf16 split (once per launch, tiny) ----------------
__global__ void wsplit_kernel(const float* __restrict__ W1, const float* __restrict__ W2,
                              const float* __restrict__ Wf1, const float* __restrict__ Wf2,
                              short* __restrict__ W1tHi, short* __restrict__ W1tLo,
                              short* __restrict__ W2tHi, short* __restrict__ W2tLo,
                              short* __restrict__ Wf1tHi, short* __restrict__ Wf1tLo,
                              short* __restrict__ Wf2tHi, short* __restrict__ Wf2tLo) {
    int i = blockIdx.x * 256 + threadIdx.x;   // grid covers 65536
    if (i < 256 * 256) {          // conv1: K=256, N=256
        int k = i >> 8, n = i & 255;
        float v = W1[i];
        unsigned short h = bf_hi(v);
        unsigned short l = bf_hi(v - bf_f(h));
        W1tHi[n * 256 + k] = (short)h;
        W1tLo[n * 256 + k] = (short)l;
    }
    if (i < 256 * 128) {          // conv2: K=256, N=128
        int k = i >> 7, n = i & 127;
        float v = W2[i];
        unsigned short h = bf_hi(v);
        unsigned short l = bf_hi(v - bf_f(h));
        W2tHi[n * 256 + k] = (short)h;
        W2tLo[n * 256 + k] = (short)l;
    }
    if (i < 64 * 256) {           // fc1: K=64, N=256
        int k = i >> 8, n = i & 255;
        float v = Wf1[i];
        unsigned short h = bf_hi(v);
        unsigned short l = bf_hi(v - bf_f(h));
        Wf1tHi[n * 64 + k] = (short)h;
        Wf1tLo[n * 64 + k] = (short)l;
    }
    if (i < 128 * 256) {          // fc2: K=128, N=256
        int k = i >> 8, n = i & 255;
        float v = Wf2[i];
        unsigned short h = bf_hi(v);
        unsigned short l = bf_hi(v - bf_f(h));
        Wf2tHi[n * 128 + k] = (short)h;
        Wf2tLo[n * 128 + k] = (short)l;
    }
}

// ---------------- split-bf16 MFMA GEMM ----------
// Block: 256 thr (4 waves, 2x2 of 64x64), tile 128x128, BK=32.
// MODE 0: v = (A@W) * rowscale[row]; MODE 1: v = (A@W) + bias[col] (ragged M guarded)
// BNRELU: A-path applies max(a*bnsc[k]+bnsh[k],0) before split (exact f32)
// OUTBF16: store v as bf16 (RNE) to OutB, else f32 to Out
template <int K, int N, int MODE, bool BNRELU, bool OUTBF16>
__global__ __launch_bounds__(256) void mfma_gemm_kernel(
    int M, const float* __restrict__ A, const short* __restrict__ WtHi,
    const short* __restrict__ WtLo, const float* __restrict__ ep,
    const float* __restrict__ bnsc, const float* __restrict__ bnsh,
    float* __restrict__ Out, short* __restrict__ OutB) {
    constexpr int LDT = 40;   // padded LDS row stride (bf16): 80 B = 20 banks -> 2-way max
    __shared__ short AsHi[128 * LDT];
    __shared__ short AsLo[128 * LDT];
    __shared__ short BsHi[128 * LDT];
    __shared__ short BsLo[128 * LDT];
    const int tid  = threadIdx.x;
    const int lane = tid & 63, wave = tid >> 6;
    const int wm = (wave >> 1) * 64, wn = (wave & 1) * 64;
    const int R0 = blockIdx.x * 128;
    const int n0 = blockIdx.y * 128;
    const int srow  = tid >> 1;          // staging row 0..127 (2 thr/row)
    const int shalf = (tid & 1) * 16;    // element offset 0 / 16
    const int l15  = lane & 15;
    const int koff = (lane >> 4) * 8;    // k-slice base per lane

    f32x4 acc[4][4];
#pragma unroll
    for (int mi = 0; mi < 4; ++mi)
#pragma unroll
        for (int ni = 0; ni < 4; ++ni)
            acc[mi][ni] = (f32x4){0.f, 0.f, 0.f, 0.f};

    const int arow = min(R0 + srow, M - 1);   // clamp for ragged tail (loads only)

    for (int k0 = 0; k0 < K; k0 += 32) {
        // ---- global loads ----
        const float4* ga = (const float4*)&A[(size_t)arow * K + k0 + shalf];
        float4 a0 = ga[0], a1 = ga[1], a2 = ga[2], a3 = ga[3];
        const int4* gwh = (const int4*)&WtHi[(size_t)(n0 + srow) * K + k0 + shalf];
        const int4* gwl = (const int4*)&WtLo[(size_t)(n0 + srow) * K + k0 + shalf];
        int4 wh0 = gwh[0], wh1 = gwh[1];
        int4 wl0 = gwl[0], wl1 = gwl[1];

        if (BNRELU) {   // fused BN-apply + ReLU on A (per-channel k)
            const float4* gs = (const float4*)&bnsc[k0 + shalf];
            const float4* gh = (const float4*)&bnsh[k0 + shalf];
            float4 s0 = gs[0], s1 = gs[1], s2 = gs[2], s3 = gs[3];
            float4 t0 = gh[0], t1 = gh[1], t2 = gh[2], t3 = gh[3];
#define BNR4(a, s, t)                                                          \
            a.x = fmaxf(a.x * s.x + t.x, 0.f);                                 \
            a.y = fmaxf(a.y * s.y + t.y, 0.f);                                 \
            a.z = fmaxf(a.z * s.z + t.z, 0.f);                                 \
            a.w = fmaxf(a.w * s.w + t.w, 0.f);
            BNR4(a0, s0, t0); BNR4(a1, s1, t1); BNR4(a2, s2, t2); BNR4(a3, s3, t3);
#undef BNR4
        }

        // ---- split A into hi/lo bf16, packed 2/word ----
        unsigned h[8], l[8];
#define SPLIT4(v, hA, hB, lA, lB)                                              \
        {                                                                      \
            unsigned short h0_ = bf_hi(v.x), h1_ = bf_hi(v.y);                 \
            unsigned short h2_ = bf_hi(v.z), h3_ = bf_hi(v.w);                 \
            unsigned short l0_ = bf_hi(v.x - bf_f(h0_));                       \
            unsigned short l1_ = bf_hi(v.y - bf_f(h1_));                       \
            unsigned short l2_ = bf_hi(v.z - bf_f(h2_));                       \
            unsigned short l3_ = bf_hi(v.w - bf_f(h3_));                       \
            hA = (unsigned)h0_ | ((unsigned)h1_ << 16);                        \
            hB = (unsigned)h2_ | ((unsigned)h3_ << 16);                        \
            lA = (unsigned)l0_ | ((unsigned)l1_ << 16);                        \
            lB = (unsigned)l2_ | ((unsigned)l3_ << 16);                        \
        }
        SPLIT4(a0, h[0], h[1], l[0], l[1]);
        SPLIT4(a1, h[2], h[3], l[2], l[3]);
        SPLIT4(a2, h[4], h[5], l[4], l[5]);
        SPLIT4(a3, h[6], h[7], l[6], l[7]);
#undef SPLIT4

        __syncthreads();   // previous iteration done reading LDS
        int4* dAH = (int4*)&AsHi[srow * LDT + shalf];
        int4* dAL = (int4*)&AsLo[srow * LDT + shalf];
        dAH[0] = make_int4((int)h[0], (int)h[1], (int)h[2], (int)h[3]);
        dAH[1] = make_int4((int)h[4], (int)h[5], (int)h[6], (int)h[7]);
        dAL[0] = make_int4((int)l[0], (int)l[1], (int)l[2], (int)l[3]);
        dAL[1] = make_int4((int)l[4], (int)l[5], (int)l[6], (int)l[7]);
        int4* dBH = (int4*)&BsHi[srow * LDT + shalf];
        int4* dBL = (int4*)&BsLo[srow * LDT + shalf];
        dBH[0] = wh0; dBH[1] = wh1;
        dBL[0] = wl0; dBL[1] = wl1;
        __syncthreads();

        // ---- fragments + MFMA (AhWh + AhWl + AlWh; fp32 accum) ----
        short8v bh[4], bl[4];
#pragma unroll
        for (int ni = 0; ni < 4; ++ni) {
            int nrow = wn + ni * 16 + l15;
            bh[ni] = *(const short8v*)&BsHi[nrow * LDT + koff];
            bl[ni] = *(const short8v*)&BsLo[nrow * LDT + koff];
        }
#pragma unroll
        for (int mi = 0; mi < 4; ++mi) {
            int mrow = wm + mi * 16 + l15;
            short8v ah = *(const short8v*)&AsHi[mrow * LDT + koff];
            short8v al = *(const short8v*)&AsLo[mrow * LDT + koff];
#pragma unroll
            for (int ni = 0; ni < 4; ++ni) {
                acc[mi][ni] = __builtin_amdgcn_mfma_f32_16x16x32_bf16(ah, bh[ni], acc[mi][ni], 0, 0, 0);
                acc[mi][ni] = __builtin_amdgcn_mfma_f32_16x16x32_bf16(ah, bl[ni], acc[mi][ni], 0, 0, 0);
                acc[mi][ni] = __builtin_amdgcn_mfma_f32_16x16x32_bf16(al, bh[ni], acc[mi][ni], 0, 0, 0);
            }
        }
    }

    // ---- epilogue: C/D layout col=lane&15, row=(lane>>4)*4+i ----
#pragma unroll
    for (int mi = 0; mi < 4; ++mi) {
#pragma unroll
        for (int i = 0; i < 4; ++i) {
            int row = R0 + wm + mi * 16 + (lane >> 4) * 4 + i;
            if (row < M) {
                float sc = (MODE == 0) ? ep[row] : 1.0f;
#pragma unroll
                for (int ni = 0; ni < 4; ++ni) {
                    int col = n0 + wn + ni * 16 + l15;
                    float v = acc[mi][ni][i];
                    v = (MODE == 0) ? v * sc : v + ep[col];
                    if (OUTBF16)
                        OutB[(size_t)row * N + col] = (short)bf_hi(v);
                    else
                        Out[(size_t)row * N + col] = v;
                }
            }
        }
    }
}

// ---------------- gather aggregation (no atomics; bf16 h, f32 accumulate/out) -------
// h pre-scaled by dinv[row]:  out[d] = bias + dinv[d]*( h'[d] + sum_{s in N(d)} h'[s] )
__device__ __forceinline__ void acc_bf4(float4& a, ushort4 v) {
    a.x += bf_f(v.x); a.y += bf_f(v.y); a.z += bf_f(v.z); a.w += bf_f(v.w);
}

__global__ __launch_bounds__(256) void gather256_kernel(const short* __restrict__ h,
                                                        const float* __restrict__ bias,
                                                        const float* __restrict__ dinv,
                                                        const int* __restrict__ rowptr,
                                                        const int* __restrict__ csr_src,
                                                        float* __restrict__ out) {
    int wid = threadIdx.x >> 6, lane = threadIdx.x & 63;   // wave per row; 4 ch/lane
    int r = blockIdx.x * 4 + wid;
    if (r >= NN) return;
    int beg = rowptr[r], end = rowptr[r + 1];
    float dr = dinv[r];
    const ushort4* hp = (const ushort4*)h;                 // row stride 64 ushort4
    float4 acc = {0.f, 0.f, 0.f, 0.f};
    acc_bf4(acc, hp[(size_t)r * 64 + lane]);               // self (pre-scaled)
    int k = beg;
    for (; k + 3 < end; k += 4) {                          // 4 row loads in flight
        int s0 = csr_src[k], s1 = csr_src[k + 1], s2 = csr_src[k + 2], s3 = csr_src[k + 3];
        ushort4 v0 = hp[(size_t)s0 * 64 + lane];
        ushort4 v1 = hp[(size_t)s1 * 64 + lane];
        ushort4 v2 = hp[(size_t)s2 * 64 + lane];
        ushort4 v3 = hp[(size_t)s3 * 64 + lane];
        acc_bf4(acc, v0); acc_bf4(acc, v1); acc_bf4(acc, v2); acc_bf4(acc, v3);
    }
    for (; k < end; ++k)
        acc_bf4(acc, hp[(size_t)csr_src[k] * 64 + lane]);
    float4 b = ((const float4*)bias)[lane];
    float4 o;
    o.x = b.x + dr * acc.x; o.y = b.y + dr * acc.y;
    o.z = b.z + dr * acc.z; o.w = b.w + dr * acc.w;
    ((float4*)(out + (size_t)r * 256))[lane] = o;
}

__global__ __launch_bounds__(256) void gather128_kernel(const short* __restrict__ h,
                                                        const float* __restrict__ bias,
                                                        const float* __restrict__ dinv,
                                                        const int* __restrict__ rowptr,
                                                        const int* __restrict__ csr_src,
                                                        float* __restrict__ out) {
    int sub = threadIdx.x >> 5, lane = threadIdx.x & 31;   // half-wave per row; 4 ch/lane
    int r = blockIdx.x * 8 + sub;
    if (r >= NN) return;
    int beg = rowptr[r], end = rowptr[r + 1];
    float dr = dinv[r];
    const ushort4* hp = (const ushort4*)h;                 // row stride 32 ushort4
    float4 acc = {0.f, 0.f, 0.f, 0.f};
    acc_bf4(acc, hp[(size_t)r * 32 + lane]);
    int k = beg;
    for (; k + 3 < end; k += 4) {
        int s0 = csr_src[k], s1 = csr_src[k + 1], s2 = csr_src[k + 2], s3 = csr_src[k + 3];
        ushort4 v0 = hp[(size_t)s0 * 32 + lane];
        ushort4 v1 = hp[(size_t)s1 * 32 + lane];
        ushort4 v2 = hp[(size_t)s2 * 32 + lane];
        ushort4 v3 = hp[(size_t)s3 * 32 + lane];
        acc_bf4(acc, v0); acc_bf4(acc, v1); acc_bf4(acc, v2); acc_bf4(acc, v3);
    }
    for (; k < end; ++k)
        acc_bf4(acc, hp[(size_t)csr_src[k] * 32 + lane]);
    float4 b = ((const float4*)bias)[lane];
    float4 o;
    o.x = b.x + dr * acc.x; o.y = b.y + dr * acc.y;
    o.z = b.z + dr * acc.z; o.w = b.w + dr * acc.w;
    ((float4*)(out + (size_t)r * 128))[lane] = o;
}

// ---------------- BN stats (vectorized, LDS-reduced) / finalize ----------------
__global__ __launch_bounds__(256) void bn_stats_kernel(const float* __restrict__ a,
                                                       float* __restrict__ sums,
                                                       float* __restrict__ sumsq) {
    __shared__ float shs[256], shs2[256];
    int tid = threadIdx.x;
    int wid = tid >> 6, lane = tid & 63;                   // 4 waves; float4/lane
    shs[tid] = 0.f; shs2[tid] = 0.f;
    __syncthreads();
    float4 s = {0.f, 0.f, 0.f, 0.f}, s2 = {0.f, 0.f, 0.f, 0.f};
    for (int row = blockIdx.x * 4 + wid; row < NN; row += gridDim.x * 4) {
        float4 v = ((const float4*)(a + (size_t)row * 256))[lane];
        s.x += v.x; s.y += v.y; s.z += v.z; s.w += v.w;
        s2.x += v.x * v.x; s2.y += v.y * v.y; s2.z += v.z * v.z; s2.w += v.w * v.w;
    }
    atomicAdd(&shs[4 * lane + 0], s.x);  atomicAdd(&shs2[4 * lane + 0], s2.x);
    atomicAdd(&shs[4 * lane + 1], s.y);  atomicAdd(&shs2[4 * lane + 1], s2.y);
    atomicAdd(&shs[4 * lane + 2], s.z);  atomicAdd(&shs2[4 * lane + 2], s2.z);
    atomicAdd(&shs[4 * lane + 3], s.w);  atomicAdd(&shs2[4 * lane + 3], s2.w);
    __syncthreads();
    atomicAdd(&sums[tid], shs[tid]);
    atomicAdd(&sumsq[tid], shs2[tid]);
}

__global__ void bn_final_kernel(const float* __restrict__ sums, const float* __restrict__ sumsq,
                                const float* __restrict__ gamma, const float* __restrict__ beta,
                                float* __restrict__ scale, float* __restrict__ shift) {
    int c = threadIdx.x;
    const float Nf = (float)NN;
    float mean = sums[c] / Nf;
    float var = sumsq[c] / Nf - mean * mean;
    float sc = gamma[c] * rsqrtf(var + BN_EPS);
    scale[c] = sc;
    shift[c] = beta[c] - mean * sc;
}

extern "C" void kernel_launch(void* const* d_in, const int* in_sizes, int n_in,
                              void* d_out, int out_size, void* d_ws, size_t ws_size,
                              hipStream_t stream) {
    const float* x       = (const float*)d_in[0];
    const float* y       = (const float*)d_in[1];
    const void*  ei      = d_in[2];
    const float* fc1_w   = (const float*)d_in[3];
    const float* fc1_b   = (const float*)d_in[4];
    const float* fc2_w   = (const float*)d_in[5];
    const float* fc2_b   = (const float*)d_in[6];
    const float* conv1_w = (const float*)d_in[7];
    const float* conv1_b = (const float*)d_in[8];
    const float* conv2_w = (const float*)d_in[9];
    const float* conv2_b = (const float*)d_in[10];
    const float* gamma   = (const float*)d_in[11];
    const float* beta    = (const float*)d_in[12];
    float* out = (float*)d_out;

    float* ws = (float*)d_ws;
    float* bufA = ws;                       // NN*256 f32: z0, then a1 (raw gather out)
    float* bufB = ws + (size_t)NN * 256;    // NN*256: h1'/h2' as bf16 (half used)
    float* aux  = bufB + (size_t)NN * 256;
    float* dinv  = aux;                      // NN
    float* sums  = dinv + NN;                // 256
    float* sumsq = sums + 256;               // 256
    float* scale = sumsq + 256;              // 256
    float* shift = scale + 256;              // 256
    int*   flag      = (int*)(shift + 256);  // 1
    int*   cnt       = flag + 1;             // NN
    int*   rowptr    = cnt + NN;             // NN+1
    int*   cursor    = rowptr + NN + 1;      // NN
    int*   blockSums = cursor + NN;          // NB_SCAN
    int*   csr_src   = blockSums + NB_SCAN + 3;  // EE
    // 16B-aligned W^T split buffers after csr
    short* w1th = (short*)(((uintptr_t)(csr_src + EE) + 15) & ~(uintptr_t)15);
    short* w1tl = w1th + 256 * 256;
    short* w2th = w1tl + 256 * 256;
    short* w2tl = w2th + 256 * 128;
    short* wf1h = w2tl + 256 * 128;
    short* wf1l = wf1h + 256 * 64;
    short* wf2h = wf1l + 256 * 64;
    short* wf2l = wf2h + 256 * 128;
    short* hB   = (short*)bufB;              // bf16 view of bufB

    // ---- CSR build + W split ----
    prep_kernel<<<320, 256, 0, stream>>>((const int*)ei, cnt, cursor, rowptr, sums, sumsq, flag);
    hist_kernel<<<1024, 256, 0, stream>>>(ei, flag, cnt);
    dinv_kernel<<<(NN + 255) / 256, 256, 0, stream>>>(cnt, dinv);
    scan1_kernel<<<NB_SCAN, 256, 0, stream>>>(cnt, rowptr, blockSums);
    scan2_kernel<<<1, 512, 0, stream>>>(blockSums);
    scan3_kernel<<<NB_SCAN, 256, 0, stream>>>(rowptr, blockSums);
    fill_kernel<<<1024, 256, 0, stream>>>(ei, flag, rowptr, cursor, csr_src);
    wsplit_kernel<<<256, 256, 0, stream>>>(conv1_w, conv2_w, fc1_w, fc2_w,
                                           w1th, w1tl, w2th, w2tl, wf1h, wf1l, wf2h, wf2l);

    // ---- input projections -> z0 in bufA (f32 out, ragged M guarded) ----
    mfma_gemm_kernel<64, 256, 1, false, false><<<dim3(469, 2), 256, 0, stream>>>(
        N_U, x, wf1h, wf1l, fc1_b, nullptr, nullptr, bufA, nullptr);
    mfma_gemm_kernel<128, 256, 1, false, false><<<dim3(157, 2), 256, 0, stream>>>(
        N_M, y, wf2h, wf2l, fc2_b, nullptr, nullptr, bufA + (size_t)N_U * 256, nullptr);

    // ---- conv1: h1' = (z0 @ W1) * dinv -> bf16 bufB; gather -> f32 bufA ----
    mfma_gemm_kernel<256, 256, 0, false, true><<<dim3(625, 2), 256, 0, stream>>>(
        NN, bufA, w1th, w1tl, dinv, nullptr, nullptr, nullptr, hB);
    gather256_kernel<<<NN / 4, 256, 0, stream>>>(hB, conv1_b, dinv, rowptr, csr_src, bufA);

    // ---- BN stats on raw a1; apply+ReLU fused into conv2's A-path ----
    bn_stats_kernel<<<256, 256, 0, stream>>>(bufA, sums, sumsq);
    bn_final_kernel<<<1, 256, 0, stream>>>(sums, sumsq, gamma, beta, scale, shift);

    // ---- conv2: h2' = (relu(bn(a1)) @ W2) * dinv -> bf16 bufB; gather -> out ----
    mfma_gemm_kernel<256, 128, 0, true, true><<<dim3(625, 1), 256, 0, stream>>>(
        NN, bufA, w2th, w2tl, dinv, scale, shift, nullptr, hB);
    gather128_kernel<<<NN / 8, 256, 0, stream>>>(hB, conv2_b, dinv, rowptr, csr_src, out);
}

// Round 8
// 398.815 us; speedup vs baseline: 7.6088x; 1.0093x over previous
//
#include <hip/hip_runtime.h>
#include <math.h>
#include <stdint.h>

#define N_U 60000
#define N_M 20000
#define NN  80000
#define EE  500000
#define BN_EPS 1e-5f
#define NB_SCAN 313   // ceil(80000/256)

typedef __attribute__((ext_vector_type(8))) short short8v;   // 8 bf16 = 4 VGPR (MFMA A/B frag)
typedef __attribute__((ext_vector_type(4))) float f32x4;     // MFMA C/D frag

// ---------------- bf16 helpers ----------------
__device__ __forceinline__ unsigned short bf_hi(float f) {
    unsigned u = __float_as_uint(f);
    return (unsigned short)((u + 0x7FFFu + ((u >> 16) & 1u)) >> 16);   // RNE
}
__device__ __forceinline__ float bf_f(unsigned short h) {
    return __uint_as_float(((unsigned)h) << 16);
}

// ---------------- prep: zero cnt/cursor/BN stats, rowptr[NN]=EE, detect edge dtype ----
__global__ void prep_kernel(const int* __restrict__ ei32, int* __restrict__ cnt,
                            int* __restrict__ cursor, int* __restrict__ rowptr,
                            float* __restrict__ sums, float* __restrict__ sumsq,
                            int* __restrict__ flag) {
    int i = blockIdx.x * blockDim.x + threadIdx.x;
    if (i < 256) { sums[i] = 0.f; sumsq[i] = 0.f; }
    for (int j = i; j < NN; j += gridDim.x * blockDim.x) { cnt[j] = 0; cursor[j] = 0; }
    if (i == 0) rowptr[NN] = EE;
    if (blockIdx.x == 0) {
        __shared__ int nz;
        if (threadIdx.x == 0) nz = 0;
        __syncthreads();
        int v = ei32[2 * threadIdx.x + 1];
        if (v != 0) atomicOr(&nz, 1);
        __syncthreads();
        if (threadIdx.x == 0) *flag = (nz == 0) ? 1 : 0;  // 1 -> int64
    }
}

__device__ __forceinline__ int load_idx(const void* ei, int f, int pos) {
    return f ? (int)((const long long*)ei)[pos] : ((const int*)ei)[pos];
}

// ---------------- degree histogram (dst side, edges only) ----------------
__global__ void hist_kernel(const void* __restrict__ ei, const int* __restrict__ flag,
                            int* __restrict__ cnt) {
    int f = *flag;
    int stride = gridDim.x * blockDim.x;
    for (int e = blockIdx.x * blockDim.x + threadIdx.x; e < EE; e += stride) {
        int d = load_idx(ei, f, EE + e);
        atomicAdd(&cnt[d], 1);
    }
}

__global__ void dinv_kernel(const int* __restrict__ cnt, float* __restrict__ dinv) {
    int i = blockIdx.x * blockDim.x + threadIdx.x;
    if (i < NN) dinv[i] = rsqrtf(1.0f + (float)cnt[i]);   // +1 self-loop
}

// ---------------- exclusive scan of cnt -> rowptr (3 kernels) ----------------
__global__ void scan1_kernel(const int* __restrict__ cnt, int* __restrict__ rowptr,
                             int* __restrict__ blockSums) {
    __shared__ int sh[256];
    int tid = threadIdx.x;
    int i = blockIdx.x * 256 + tid;
    int v = (i < NN) ? cnt[i] : 0;
    int x = v;
    sh[tid] = x; __syncthreads();
#pragma unroll
    for (int off = 1; off < 256; off <<= 1) {
        int t = (tid >= off) ? sh[tid - off] : 0;
        __syncthreads();
        x += t; sh[tid] = x;
        __syncthreads();
    }
    if (i < NN) rowptr[i] = x - v;
    if (tid == 255) blockSums[blockIdx.x] = x;
}

__global__ void scan2_kernel(int* __restrict__ blockSums) {
    __shared__ int sh[512];
    int tid = threadIdx.x;
    int v = (tid < NB_SCAN) ? blockSums[tid] : 0;
    int x = v;
    sh[tid] = x; __syncthreads();
#pragma unroll
    for (int off = 1; off < 512; off <<= 1) {
        int t = (tid >= off) ? sh[tid - off] : 0;
        __syncthreads();
        x += t; sh[tid] = x;
        __syncthreads();
    }
    if (tid < NB_SCAN) blockSums[tid] = x - v;
}

__global__ void scan3_kernel(int* __restrict__ rowptr, const int* __restrict__ blockSums) {
    int i = blockIdx.x * 256 + threadIdx.x;
    if (i < NN) rowptr[i] += blockSums[blockIdx.x];
}

// ---------------- CSR fill: csr_src grouped by dst ----------------
__global__ void fill_kernel(const void* __restrict__ ei, const int* __restrict__ flag,
                            const int* __restrict__ rowptr, int* __restrict__ cursor,
                            int* __restrict__ csr_src) {
    int f = *flag;
    int stride = gridDim.x * blockDim.x;
    for (int e = blockIdx.x * blockDim.x + threadIdx.x; e < EE; e += stride) {
        int s = load_idx(ei, f, e);
        int d = load_idx(ei, f, EE + e);
        int pos = rowptr[d] + atomicAdd(&cursor[d], 1);
        csr_src[pos] = s;
    }
}

// ---------------- W split into MFMA-fragment order (once per launch, tiny) ----------
// W[K][N] f32 row-major.  Fragment layout: for n-tile nt (16 cols) and k-tile kt
// (32 k), lane l = q*16+r holds cols nt*16+r, k = kt*32+q*8+p (p=0..7):
//   idx = (nt*(K/32)+kt)*512 + q*128 + r*8 + p
// so a wave's B-fragment load is one contiguous 1 KiB read (16 B/lane).
template <int K, int N>
__global__ void wsplit_frag_kernel(const float* __restrict__ W,
                                   short* __restrict__ Hi, short* __restrict__ Lo) {
    int i = blockIdx.x * 256 + threadIdx.x;
    if (i >= K * N) return;
    int k = i / N, n = i - k * N;
    float v = W[i];
    unsigned short h = bf_hi(v);
    unsigned short l = bf_hi(v - bf_f(h));
    int nt = n >> 4, r = n & 15, kt = k >> 5, q = (k >> 3) & 3, p = k & 7;
    int idx = ((nt * (K / 32) + kt) << 9) + (q << 7) + (r << 3) + p;
    Hi[idx] = (short)h;
    Lo[idx] = (short)l;
}

// ---------------- split-bf16 MFMA GEMM (A via LDS, W via fragment-ordered L2) -------
// Block: 256 thr (4 waves, 2x2 of 64x64), tile 128x128, BK=32. LDS = A hi/lo only.
// Pipeline: split+write tile kt -> prefetch A tile kt+1 -> W-frag loads + MFMA (T14).
// MODE 0: v = (A@W) * rowscale[row]; MODE 1: v = (A@W) + bias[col] (ragged M guarded)
// BNRELU: A-path applies max(a*bnsc[k]+bnsh[k],0) before split (exact f32)
// OUTBF16: store v as bf16 (RNE) to OutB, else f32 to Out
template <int K, int N, int MODE, bool BNRELU, bool OUTBF16>
__global__ __launch_bounds__(256) void mfma_gemm_kernel(
    int M, const float* __restrict__ A, const short* __restrict__ WfHi,
    const short* __restrict__ WfLo, const float* __restrict__ ep,
    const float* __restrict__ bnsc, const float* __restrict__ bnsh,
    float* __restrict__ Out, short* __restrict__ OutB) {
    constexpr int LDT = 40;   // padded LDS row stride (bf16): 80 B = 5x16B -> uniform slots
    constexpr int NT = K / 32;
    __shared__ short AsHi[128 * LDT];
    __shared__ short AsLo[128 * LDT];
    const int tid  = threadIdx.x;
    const int lane = tid & 63, wave = tid >> 6;
    const int wm = (wave >> 1) * 64, wn = (wave & 1) * 64;
    const int R0 = blockIdx.x * 128;
    const int n0 = blockIdx.y * 128;
    const int srow  = tid >> 1;          // staging row 0..127 (2 thr/row)
    const int shalf = (tid & 1) * 16;    // element offset 0 / 16
    const int l15  = lane & 15;
    const int koff = (lane >> 4) * 8;    // k-slice base per lane
    const int nt0  = (n0 + wn) >> 4;     // base n-tile of this wave

    f32x4 acc[4][4];
#pragma unroll
    for (int mi = 0; mi < 4; ++mi)
#pragma unroll
        for (int ni = 0; ni < 4; ++ni)
            acc[mi][ni] = (f32x4){0.f, 0.f, 0.f, 0.f};

    const int arow = min(R0 + srow, M - 1);   // clamp for ragged tail (loads only)
    const float* abase = &A[(size_t)arow * K + shalf];

    // ---- prologue: load A tile 0 into registers ----
    float4 a0 = ((const float4*)abase)[0];
    float4 a1 = ((const float4*)abase)[1];
    float4 a2 = ((const float4*)abase)[2];
    float4 a3 = ((const float4*)abase)[3];

#pragma unroll
    for (int kt = 0; kt < NT; ++kt) {
        const int k0 = kt * 32;

        if (BNRELU) {   // fused BN-apply + ReLU on A (per-channel k), exact f32
            const float4* gs = (const float4*)&bnsc[k0 + shalf];
            const float4* gh = (const float4*)&bnsh[k0 + shalf];
            float4 s0 = gs[0], s1 = gs[1], s2 = gs[2], s3 = gs[3];
            float4 t0 = gh[0], t1 = gh[1], t2 = gh[2], t3 = gh[3];
#define BNR4(a, s, t)                                                          \
            a.x = fmaxf(a.x * s.x + t.x, 0.f);                                 \
            a.y = fmaxf(a.y * s.y + t.y, 0.f);                                 \
            a.z = fmaxf(a.z * s.z + t.z, 0.f);                                 \
            a.w = fmaxf(a.w * s.w + t.w, 0.f);
            BNR4(a0, s0, t0); BNR4(a1, s1, t1); BNR4(a2, s2, t2); BNR4(a3, s3, t3);
#undef BNR4
        }

        // ---- split A into hi/lo bf16, packed 2/word ----
        unsigned h[8], l[8];
#define SPLIT4(v, hA, hB, lA, lB)                                              \
        {                                                                      \
            unsigned short h0_ = bf_hi(v.x), h1_ = bf_hi(v.y);                 \
            unsigned short h2_ = bf_hi(v.z), h3_ = bf_hi(v.w);                 \
            unsigned short l0_ = bf_hi(v.x - bf_f(h0_));                       \
            unsigned short l1_ = bf_hi(v.y - bf_f(h1_));                       \
            unsigned short l2_ = bf_hi(v.z - bf_f(h2_));                       \
            unsigned short l3_ = bf_hi(v.w - bf_f(h3_));                       \
            hA = (unsigned)h0_ | ((unsigned)h1_ << 16);                        \
            hB = (unsigned)h2_ | ((unsigned)h3_ << 16);                        \
            lA = (unsigned)l0_ | ((unsigned)l1_ << 16);                        \
            lB = (unsigned)l2_ | ((unsigned)l3_ << 16);                        \
        }
        SPLIT4(a0, h[0], h[1], l[0], l[1]);
        SPLIT4(a1, h[2], h[3], l[2], l[3]);
        SPLIT4(a2, h[4], h[5], l[4], l[5]);
        SPLIT4(a3, h[6], h[7], l[6], l[7]);
#undef SPLIT4

        __syncthreads();   // previous iteration done reading LDS
        int4* dAH = (int4*)&AsHi[srow * LDT + shalf];
        int4* dAL = (int4*)&AsLo[srow * LDT + shalf];
        dAH[0] = make_int4((int)h[0], (int)h[1], (int)h[2], (int)h[3]);
        dAH[1] = make_int4((int)h[4], (int)h[5], (int)h[6], (int)h[7]);
        dAL[0] = make_int4((int)l[0], (int)l[1], (int)l[2], (int)l[3]);
        dAL[1] = make_int4((int)l[4], (int)l[5], (int)l[6], (int)l[7]);
        __syncthreads();

        // ---- prefetch next A tile (latency hides under MFMA below) ----
        if (kt + 1 < NT) {
            const float4* gnext = (const float4*)(abase + (kt + 1) * 32);
            a0 = gnext[0]; a1 = gnext[1]; a2 = gnext[2]; a3 = gnext[3];
        }

        // ---- W fragments straight from global (L2-resident, fully coalesced) ----
        short8v bh[4], bl[4];
#pragma unroll
        for (int ni = 0; ni < 4; ++ni) {
            int fidx = (((nt0 + ni) * NT + kt) << 9) + lane * 8;
            bh[ni] = *(const short8v*)&WfHi[fidx];
            bl[ni] = *(const short8v*)&WfLo[fidx];
        }

        // ---- A frags + MFMA (AhWh + AhWl + AlWh; fp32 accum) ----
#pragma unroll
        for (int mi = 0; mi < 4; ++mi) {
            int mrow = wm + mi * 16 + l15;
            short8v ah = *(const short8v*)&AsHi[mrow * LDT + koff];
            short8v al = *(const short8v*)&AsLo[mrow * LDT + koff];
#pragma unroll
            for (int ni = 0; ni < 4; ++ni) {
                acc[mi][ni] = __builtin_amdgcn_mfma_f32_16x16x32_bf16(ah, bh[ni], acc[mi][ni], 0, 0, 0);
                acc[mi][ni] = __builtin_amdgcn_mfma_f32_16x16x32_bf16(ah, bl[ni], acc[mi][ni], 0, 0, 0);
                acc[mi][ni] = __builtin_amdgcn_mfma_f32_16x16x32_bf16(al, bh[ni], acc[mi][ni], 0, 0, 0);
            }
        }
    }

    // ---- epilogue: C/D layout col=lane&15, row=(lane>>4)*4+i ----
#pragma unroll
    for (int mi = 0; mi < 4; ++mi) {
#pragma unroll
        for (int i = 0; i < 4; ++i) {
            int row = R0 + wm + mi * 16 + (lane >> 4) * 4 + i;
            if (row < M) {
                float sc = (MODE == 0) ? ep[row] : 1.0f;
#pragma unroll
                for (int ni = 0; ni < 4; ++ni) {
                    int col = n0 + wn + ni * 16 + l15;
                    float v = acc[mi][ni][i];
                    v = (MODE == 0) ? v * sc : v + ep[col];
                    if (OUTBF16)
                        OutB[(size_t)row * N + col] = (short)bf_hi(v);
                    else
                        Out[(size_t)row * N + col] = v;
                }
            }
        }
    }
}

// ---------------- gather aggregation (no atomics; bf16 h, f32 accumulate/out) -------
// h pre-scaled by dinv[row]:  out[d] = bias + dinv[d]*( h'[d] + sum_{s in N(d)} h'[s] )
__device__ __forceinline__ void acc_bf4(float4& a, ushort4 v) {
    a.x += bf_f(v.x); a.y += bf_f(v.y); a.z += bf_f(v.z); a.w += bf_f(v.w);
}

__global__ __launch_bounds__(256) void gather256_kernel(const short* __restrict__ h,
                                                        const float* __restrict__ bias,
                                                        const float* __restrict__ dinv,
                                                        const int* __restrict__ rowptr,
                                                        const int* __restrict__ csr_src,
                                                        float* __restrict__ out) {
    int wid = threadIdx.x >> 6, lane = threadIdx.x & 63;   // wave per row; 4 ch/lane
    int r = blockIdx.x * 4 + wid;
    if (r >= NN) return;
    int beg = rowptr[r], end = rowptr[r + 1];
    float dr = dinv[r];
    const ushort4* hp = (const ushort4*)h;                 // row stride 64 ushort4
    float4 acc = {0.f, 0.f, 0.f, 0.f};
    acc_bf4(acc, hp[(size_t)r * 64 + lane]);               // self (pre-scaled)
    int k = beg;
    for (; k + 3 < end; k += 4) {                          // 4 row loads in flight
        int s0 = csr_src[k], s1 = csr_src[k + 1], s2 = csr_src[k + 2], s3 = csr_src[k + 3];
        ushort4 v0 = hp[(size_t)s0 * 64 + lane];
        ushort4 v1 = hp[(size_t)s1 * 64 + lane];
        ushort4 v2 = hp[(size_t)s2 * 64 + lane];
        ushort4 v3 = hp[(size_t)s3 * 64 + lane];
        acc_bf4(acc, v0); acc_bf4(acc, v1); acc_bf4(acc, v2); acc_bf4(acc, v3);
    }
    for (; k < end; ++k)
        acc_bf4(acc, hp[(size_t)csr_src[k] * 64 + lane]);
    float4 b = ((const float4*)bias)[lane];
    float4 o;
    o.x = b.x + dr * acc.x; o.y = b.y + dr * acc.y;
    o.z = b.z + dr * acc.z; o.w = b.w + dr * acc.w;
    ((float4*)(out + (size_t)r * 256))[lane] = o;
}

__global__ __launch_bounds__(256) void gather128_kernel(const short* __restrict__ h,
                                                        const float* __restrict__ bias,
                                                        const float* __restrict__ dinv,
                                                        const int* __restrict__ rowptr,
                                                        const int* __restrict__ csr_src,
                                                        float* __restrict__ out) {
    int sub = threadIdx.x >> 5, lane = threadIdx.x & 31;   // half-wave per row; 4 ch/lane
    int r = blockIdx.x * 8 + sub;
    if (r >= NN) return;
    int beg = rowptr[r], end = rowptr[r + 1];
    float dr = dinv[r];
    const ushort4* hp = (const ushort4*)h;                 // row stride 32 ushort4
    float4 acc = {0.f, 0.f, 0.f, 0.f};
    acc_bf4(acc, hp[(size_t)r * 32 + lane]);
    int k = beg;
    for (; k + 3 < end; k += 4) {
        int s0 = csr_src[k], s1 = csr_src[k + 1], s2 = csr_src[k + 2], s3 = csr_src[k + 3];
        ushort4 v0 = hp[(size_t)s0 * 32 + lane];
        ushort4 v1 = hp[(size_t)s1 * 32 + lane];
        ushort4 v2 = hp[(size_t)s2 * 32 + lane];
        ushort4 v3 = hp[(size_t)s3 * 32 + lane];
        acc_bf4(acc, v0); acc_bf4(acc, v1); acc_bf4(acc, v2); acc_bf4(acc, v3);
    }
    for (; k < end; ++k)
        acc_bf4(acc, hp[(size_t)csr_src[k] * 32 + lane]);
    float4 b = ((const float4*)bias)[lane];
    float4 o;
    o.x = b.x + dr * acc.x; o.y = b.y + dr * acc.y;
    o.z = b.z + dr * acc.z; o.w = b.w + dr * acc.w;
    ((float4*)(out + (size_t)r * 128))[lane] = o;
}

// ---------------- BN stats (vectorized, LDS-reduced) / finalize ----------------
__global__ __launch_bounds__(256) void bn_stats_kernel(const float* __restrict__ a,
                                                       float* __restrict__ sums,
                                                       float* __restrict__ sumsq) {
    __shared__ float shs[256], shs2[256];
    int tid = threadIdx.x;
    int wid = tid >> 6, lane = tid & 63;                   // 4 waves; float4/lane
    shs[tid] = 0.f; shs2[tid] = 0.f;
    __syncthreads();
    float4 s = {0.f, 0.f, 0.f, 0.f}, s2 = {0.f, 0.f, 0.f, 0.f};
    for (int row = blockIdx.x * 4 + wid; row < NN; row += gridDim.x * 4) {
        float4 v = ((const float4*)(a + (size_t)row * 256))[lane];
        s.x += v.x; s.y += v.y; s.z += v.z; s.w += v.w;
        s2.x += v.x * v.x; s2.y += v.y * v.y; s2.z += v.z * v.z; s2.w += v.w * v.w;
    }
    atomicAdd(&shs[4 * lane + 0], s.x);  atomicAdd(&shs2[4 * lane + 0], s2.x);
    atomicAdd(&shs[4 * lane + 1], s.y);  atomicAdd(&shs2[4 * lane + 1], s2.y);
    atomicAdd(&shs[4 * lane + 2], s.z);  atomicAdd(&shs2[4 * lane + 2], s2.z);
    atomicAdd(&shs[4 * lane + 3], s.w);  atomicAdd(&shs2[4 * lane + 3], s2.w);
    __syncthreads();
    atomicAdd(&sums[tid], shs[tid]);
    atomicAdd(&sumsq[tid], shs2[tid]);
}

__global__ void bn_final_kernel(const float* __restrict__ sums, const float* __restrict__ sumsq,
                                const float* __restrict__ gamma, const float* __restrict__ beta,
                                float* __restrict__ scale, float* __restrict__ shift) {
    int c = threadIdx.x;
    const float Nf = (float)NN;
    float mean = sums[c] / Nf;
    float var = sumsq[c] / Nf - mean * mean;
    float sc = gamma[c] * rsqrtf(var + BN_EPS);
    scale[c] = sc;
    shift[c] = beta[c] - mean * sc;
}

extern "C" void kernel_launch(void* const* d_in, const int* in_sizes, int n_in,
                              void* d_out, int out_size, void* d_ws, size_t ws_size,
                              hipStream_t stream) {
    const float* x       = (const float*)d_in[0];
    const float* y       = (const float*)d_in[1];
    const void*  ei      = d_in[2];
    const float* fc1_w   = (const float*)d_in[3];
    const float* fc1_b   = (const float*)d_in[4];
    const float* fc2_w   = (const float*)d_in[5];
    const float* fc2_b   = (const float*)d_in[6];
    const float* conv1_w = (const float*)d_in[7];
    const float* conv1_b = (const float*)d_in[8];
    const float* conv2_w = (const float*)d_in[9];
    const float* conv2_b = (const float*)d_in[10];
    const float* gamma   = (const float*)d_in[11];
    const float* beta    = (const float*)d_in[12];
    float* out = (float*)d_out;

    float* ws = (float*)d_ws;
    float* bufA = ws;                       // NN*256 f32: z0, then a1 (raw gather out)
    float* bufB = ws + (size_t)NN * 256;    // NN*256: h1'/h2' as bf16 (half used)
    float* aux  = bufB + (size_t)NN * 256;
    float* dinv  = aux;                      // NN
    float* sums  = dinv + NN;                // 256
    float* sumsq = sums + 256;               // 256
    float* scale = sumsq + 256;              // 256
    float* shift = scale + 256;              // 256
    int*   flag      = (int*)(shift + 256);  // 1
    int*   cnt       = flag + 1;             // NN
    int*   rowptr    = cnt + NN;             // NN+1
    int*   cursor    = rowptr + NN + 1;      // NN
    int*   blockSums = cursor + NN;          // NB_SCAN
    int*   csr_src   = blockSums + NB_SCAN + 3;  // EE
    // 16B-aligned fragment-ordered W buffers after csr
    short* w1th = (short*)(((uintptr_t)(csr_src + EE) + 15) & ~(uintptr_t)15);
    short* w1tl = w1th + 256 * 256;
    short* w2th = w1tl + 256 * 256;
    short* w2tl = w2th + 256 * 128;
    short* wf1h = w2tl + 256 * 128;
    short* wf1l = wf1h + 256 * 64;
    short* wf2h = wf1l + 256 * 64;
    short* wf2l = wf2h + 256 * 128;
    short* hB   = (short*)bufB;              // bf16 view of bufB

    // ---- CSR build + W fragment split ----
    prep_kernel<<<320, 256, 0, stream>>>((const int*)ei, cnt, cursor, rowptr, sums, sumsq, flag);
    hist_kernel<<<1024, 256, 0, stream>>>(ei, flag, cnt);
    dinv_kernel<<<(NN + 255) / 256, 256, 0, stream>>>(cnt, dinv);
    scan1_kernel<<<NB_SCAN, 256, 0, stream>>>(cnt, rowptr, blockSums);
    scan2_kernel<<<1, 512, 0, stream>>>(blockSums);
    scan3_kernel<<<NB_SCAN, 256, 0, stream>>>(rowptr, blockSums);
    fill_kernel<<<1024, 256, 0, stream>>>(ei, flag, rowptr, cursor, csr_src);
    wsplit_frag_kernel<256, 256><<<256, 256, 0, stream>>>(conv1_w, w1th, w1tl);
    wsplit_frag_kernel<256, 128><<<128, 256, 0, stream>>>(conv2_w, w2th, w2tl);
    wsplit_frag_kernel<64, 256><<<64, 256, 0, stream>>>(fc1_w, wf1h, wf1l);
    wsplit_frag_kernel<128, 256><<<128, 256, 0, stream>>>(fc2_w, wf2h, wf2l);

    // ---- input projections -> z0 in bufA (f32 out, ragged M guarded) ----
    mfma_gemm_kernel<64, 256, 1, false, false><<<dim3(469, 2), 256, 0, stream>>>(
        N_U, x, wf1h, wf1l, fc1_b, nullptr, nullptr, bufA, nullptr);
    mfma_gemm_kernel<128, 256, 1, false, false><<<dim3(157, 2), 256, 0, stream>>>(
        N_M, y, wf2h, wf2l, fc2_b, nullptr, nullptr, bufA + (size_t)N_U * 256, nullptr);

    // ---- conv1: h1' = (z0 @ W1) * dinv -> bf16 bufB; gather -> f32 bufA ----
    mfma_gemm_kernel<256, 256, 0, false, true><<<dim3(625, 2), 256, 0, stream>>>(
        NN, bufA, w1th, w1tl, dinv, nullptr, nullptr, nullptr, hB);
    gather256_kernel<<<NN / 4, 256, 0, stream>>>(hB, conv1_b, dinv, rowptr, csr_src, bufA);

    // ---- BN stats on raw a1; apply+ReLU fused into conv2's A-path ----
    bn_stats_kernel<<<256, 256, 0, stream>>>(bufA, sums, sumsq);
    bn_final_kernel<<<1, 256, 0, stream>>>(sums, sumsq, gamma, beta, scale, shift);

    // ---- conv2: h2' = (relu(bn(a1)) @ W2) * dinv -> bf16 bufB; gather -> out ----
    mfma_gemm_kernel<256, 128, 0, true, true><<<dim3(625, 1), 256, 0, stream>>>(
        NN, bufA, w2th, w2tl, dinv, scale, shift, nullptr, hB);
    gather128_kernel<<<NN / 8, 256, 0, stream>>>(hB, conv2_b, dinv, rowptr, csr_src, out);
}